// Round 5
// baseline (303.366 us; speedup 1.0000x reference)
//
#include <hip/hip_runtime.h>
#include <hip/hip_bf16.h>

#define N_NODES 50000
#define N_EDGES 800000
#define D 128

#define SCAN_NBLOCKS ((N_NODES + 255) / 256)   // 196

using bf16x8 = __attribute__((ext_vector_type(8))) short;   // 8 bf16 (4 VGPRs)
using f32x4  = __attribute__((ext_vector_type(4))) float;   // MFMA C/D

static __device__ __forceinline__ ushort f2bf(float f) {
    __hip_bfloat16 h = __float2bfloat16(f);   // RNE
    return *reinterpret_cast<ushort*>(&h);
}

// ---------------------------------------------------------------------------
// ws layout (~3.8 MB): cnt, off, cursor, blockoff, sorted_src
// d_out written once by the fused kernel (no scratch aliasing anymore).
// ---------------------------------------------------------------------------

__global__ void init_ws(int* __restrict__ cnt, int* __restrict__ cursor) {
    int i = blockIdx.x * 256 + threadIdx.x;
    if (i < N_NODES) { cnt[i] = 0; cursor[i] = 0; }
}

__global__ void histogram(const int* __restrict__ dst, int* __restrict__ cnt) {
    int e = blockIdx.x * 256 + threadIdx.x;
    if (e >= N_EDGES) return;
    atomicAdd(&cnt[dst[e]], 1);
}

// 3-phase parallel exclusive scan (R3: replaced 94us single-block scan)
__global__ void __launch_bounds__(256)
scan_reduce(const int* __restrict__ cnt, int* __restrict__ blocksum) {
    int i = blockIdx.x * 256 + threadIdx.x;
    int v = (i < N_NODES) ? cnt[i] : 0;
#pragma unroll
    for (int o = 32; o; o >>= 1) v += __shfl_down(v, o, 64);
    __shared__ int ws_[4];
    if ((threadIdx.x & 63) == 0) ws_[threadIdx.x >> 6] = v;
    __syncthreads();
    if (threadIdx.x == 0)
        blocksum[blockIdx.x] = ws_[0] + ws_[1] + ws_[2] + ws_[3];
}

__global__ void __launch_bounds__(256)
scan_partials(const int* __restrict__ blocksum, int* __restrict__ blockoff,
              int* __restrict__ off) {
    __shared__ int sh[256];
    int t = threadIdx.x;
    int v = (t < SCAN_NBLOCKS) ? blocksum[t] : 0;
    sh[t] = v;
    __syncthreads();
    for (int o = 1; o < 256; o <<= 1) {
        int n = (t >= o) ? sh[t - o] : 0;
        __syncthreads();
        sh[t] += n;
        __syncthreads();
    }
    if (t < SCAN_NBLOCKS) blockoff[t] = sh[t] - v;      // exclusive
    if (t == SCAN_NBLOCKS - 1) off[N_NODES] = sh[t];    // total
}

__global__ void __launch_bounds__(256)
scan_final(const int* __restrict__ cnt, const int* __restrict__ blockoff,
           int* __restrict__ off) {
    int i = blockIdx.x * 256 + threadIdx.x;
    int lane = threadIdx.x & 63;
    int w    = threadIdx.x >> 6;
    int v = (i < N_NODES) ? cnt[i] : 0;
    int incl = v;
#pragma unroll
    for (int o = 1; o < 64; o <<= 1) {
        int n = __shfl_up(incl, o, 64);
        if (lane >= o) incl += n;
    }
    __shared__ int wsum[4];
    if (lane == 63) wsum[w] = incl;
    __syncthreads();
    int wofs = 0;
    for (int j = 0; j < w; ++j) wofs += wsum[j];
    if (i < N_NODES) off[i] = incl - v + wofs + blockoff[blockIdx.x];
}

__global__ void build_sorted(const int* __restrict__ src, const int* __restrict__ dst,
                             const int* __restrict__ off, int* __restrict__ cursor,
                             int* __restrict__ sorted_src) {
    int e = blockIdx.x * 256 + threadIdx.x;
    if (e >= N_EDGES) return;
    int d = dst[e];
    int p = off[d] + atomicAdd(&cursor[d], 1);
    sorted_src[p] = src[e];
}

// ---------------------------------------------------------------------------
// Fused gather-sum + bf16-MFMA GEMM + relu + residual.
// Block = 256 (4 waves), 16 nodes per wave, 64 nodes per block.
// LDS: Wl = W in bf16, chunk-major [k/8][o][8] so B-frag ds_read_b128 are
//      contiguous 1KB/wave (conflict-free).
//      Al = per-wave 16x136 bf16 rows (stride 136 shorts = 272B: gather
//      writes are 256B-contiguous 2-way = free; padded reads avoid the
//      stride-256B all-lanes-one-bank pathology).
// MFMA: D = A * B, A[m][k] = agg_bf16 (m=lane&15, k=quad*8+j),
//       B[k][n] = W[n][k]  (W natural row-major!)  => D = agg @ W.T.
// ---------------------------------------------------------------------------
__global__ void __launch_bounds__(256)
gather_gemm(const float* __restrict__ x,
            const int* __restrict__ sorted_src,
            const int* __restrict__ off,
            const float* __restrict__ W,
            float* __restrict__ out) {
    __shared__ ushort Wl[128 * 128];        // 32 KB, chunk-major
    __shared__ ushort Al[4 * 16 * 136];     // 17 KB, per-wave rows

    const int tid  = threadIdx.x;
    const int lane = tid & 63;
    const int wv   = tid >> 6;
    const int m16  = lane & 15;
    const int q    = lane >> 4;

    // ---- stage W -> LDS (bf16, chunked): chunk g = kc*128 + o ----
#pragma unroll
    for (int i = 0; i < 8; ++i) {
        int g  = tid + i * 256;            // 0..2047
        int o  = g & 127;
        int kc = g >> 7;
        const float4* wp = (const float4*)(W + (size_t)o * D + kc * 8);
        float4 w0 = wp[0], w1 = wp[1];
        bf16x8 h;
        h[0] = (short)f2bf(w0.x); h[1] = (short)f2bf(w0.y);
        h[2] = (short)f2bf(w0.z); h[3] = (short)f2bf(w0.w);
        h[4] = (short)f2bf(w1.x); h[5] = (short)f2bf(w1.y);
        h[6] = (short)f2bf(w1.z); h[7] = (short)f2bf(w1.w);
        *(bf16x8*)&Wl[g * 8] = h;          // consecutive tids -> consecutive 16B
    }
    __syncthreads();

    const int nb = blockIdx.x * 64 + wv * 16;
    ushort* Aw = &Al[wv * (16 * 136)];

    // ---- gather: one node at a time, lane holds cols 2l,2l+1 (fp32 acc) ----
    for (int m = 0; m < 16; ++m) {
        int node = nb + m;
        float ax = 0.f, ay = 0.f;
        if (node < N_NODES) {
            int e   = off[node];
            int end = off[node + 1];
            const float* xb = x + (size_t)lane * 2;
            for (; e + 3 < end; e += 4) {
                int s0 = sorted_src[e],     s1 = sorted_src[e + 1];
                int s2 = sorted_src[e + 2], s3 = sorted_src[e + 3];
                float2 v0 = *(const float2*)(xb + (size_t)s0 * D);
                float2 v1 = *(const float2*)(xb + (size_t)s1 * D);
                float2 v2 = *(const float2*)(xb + (size_t)s2 * D);
                float2 v3 = *(const float2*)(xb + (size_t)s3 * D);
                ax += (v0.x + v1.x) + (v2.x + v3.x);
                ay += (v0.y + v1.y) + (v2.y + v3.y);
            }
            for (; e < end; ++e) {
                float2 v = *(const float2*)(xb + (size_t)sorted_src[e] * D);
                ax += v.x; ay += v.y;
            }
        }
        ushort2 p = make_ushort2(f2bf(ax), f2bf(ay));
        *(ushort2*)&Aw[m * 136 + lane * 2] = p;    // 256B contiguous, bank-free
    }
    // (reads below are same-wave: compiler inserts lgkmcnt wait, no barrier)

    // ---- A fragments: 4 K-chunks of this wave's 16 rows ----
    bf16x8 a[4];
#pragma unroll
    for (int kb = 0; kb < 4; ++kb)
        a[kb] = *(const bf16x8*)&Aw[m16 * 136 + kb * 32 + q * 8];

    // ---- 8 output tiles of 16 cols each ----
#pragma unroll
    for (int t = 0; t < 8; ++t) {
        f32x4 acc = {0.f, 0.f, 0.f, 0.f};
#pragma unroll
        for (int kb = 0; kb < 4; ++kb) {
            bf16x8 b = *(const bf16x8*)&Wl[(((kb * 4 + q) * 128) + t * 16 + m16) * 8];
            acc = __builtin_amdgcn_mfma_f32_16x16x32_bf16(a[kb], b, acc, 0, 0, 0);
        }
        const int col = t * 16 + m16;
        const int r0  = q * 4;
#pragma unroll
        for (int r = 0; r < 4; ++r) {
            int node = nb + r0 + r;
            if (node < N_NODES) {
                size_t idx = (size_t)node * D + col;
                out[idx] = fmaxf(acc[r], 0.f) + x[idx];
            }
        }
    }
}

extern "C" void kernel_launch(void* const* d_in, const int* in_sizes, int n_in,
                              void* d_out, int out_size, void* d_ws, size_t ws_size,
                              hipStream_t stream) {
    const float* x   = (const float*)d_in[0];
    const int*   src = (const int*)d_in[1];   // harness passes integers as int32
    const int*   dst = (const int*)d_in[2];
    const float* W   = (const float*)d_in[3];
    float* out = (float*)d_out;

    char* ws = (char*)d_ws;
    int* cnt        = (int*)ws;   ws += (size_t)N_NODES * 4;
    int* off        = (int*)ws;   ws += (size_t)(N_NODES + 1) * 4;
    int* cursor     = (int*)ws;   ws += (size_t)N_NODES * 4;
    int* blockoff   = (int*)ws;   ws += (size_t)SCAN_NBLOCKS * 4;
    int* sorted_src = (int*)ws;

    init_ws<<<(N_NODES + 255) / 256, 256, 0, stream>>>(cnt, cursor);
    histogram<<<(N_EDGES + 255) / 256, 256, 0, stream>>>(dst, cnt);
    scan_reduce<<<SCAN_NBLOCKS, 256, 0, stream>>>(cnt, blockoff /*blocksum*/);
    scan_partials<<<1, 256, 0, stream>>>(blockoff, blockoff, off);  // in-place safe: 1 block
    scan_final<<<SCAN_NBLOCKS, 256, 0, stream>>>(cnt, blockoff, off);
    build_sorted<<<(N_EDGES + 255) / 256, 256, 0, stream>>>(src, dst, off, cursor, sorted_src);

    gather_gemm<<<(N_NODES + 63) / 64, 256, 0, stream>>>(x, sorted_src, off, W, out);
}

// Round 6
// 253.618 us; speedup vs baseline: 1.1962x; 1.1962x over previous
//
#include <hip/hip_runtime.h>
#include <hip/hip_bf16.h>

#define N_NODES 50000
#define N_EDGES 800000
#define D 128

#define SCAN_NBLOCKS ((N_NODES + 255) / 256)   // 196

using bf16x8 = __attribute__((ext_vector_type(8))) short;   // 8 bf16 (4 VGPRs)
using f32x4  = __attribute__((ext_vector_type(4))) float;   // MFMA C/D

static __device__ __forceinline__ ushort f2bf(float f) {
    __hip_bfloat16 h = __float2bfloat16(f);   // RNE
    return *reinterpret_cast<ushort*>(&h);
}

// ---------------------------------------------------------------------------
// ws layout: cnt[N], off[N+1], cursor[N], blockoff[196], sorted_src[E] (~4 MB)
// d_out: gather_sum writes agg rows; gemm transforms rows in place (each
// block exclusively owns its 64 rows: all loads of a row precede its store
// within the owning wave).
// ---------------------------------------------------------------------------

// 4 edges/thread, int4 loads. Non-returning int atomics.
__global__ void __launch_bounds__(256)
histogram(const int* __restrict__ dst, int* __restrict__ cnt) {
    int i = blockIdx.x * 256 + threadIdx.x;
    if (i >= N_EDGES / 4) return;
    int4 d = ((const int4*)dst)[i];
    atomicAdd(&cnt[d.x], 1);
    atomicAdd(&cnt[d.y], 1);
    atomicAdd(&cnt[d.z], 1);
    atomicAdd(&cnt[d.w], 1);
}

// 3-phase parallel exclusive scan (R3)
__global__ void __launch_bounds__(256)
scan_reduce(const int* __restrict__ cnt, int* __restrict__ blocksum) {
    int i = blockIdx.x * 256 + threadIdx.x;
    int v = (i < N_NODES) ? cnt[i] : 0;
#pragma unroll
    for (int o = 32; o; o >>= 1) v += __shfl_down(v, o, 64);
    __shared__ int ws_[4];
    if ((threadIdx.x & 63) == 0) ws_[threadIdx.x >> 6] = v;
    __syncthreads();
    if (threadIdx.x == 0)
        blocksum[blockIdx.x] = ws_[0] + ws_[1] + ws_[2] + ws_[3];
}

__global__ void __launch_bounds__(256)
scan_partials(const int* __restrict__ blocksum, int* __restrict__ blockoff,
              int* __restrict__ off) {
    __shared__ int sh[256];
    int t = threadIdx.x;
    int v = (t < SCAN_NBLOCKS) ? blocksum[t] : 0;
    sh[t] = v;
    __syncthreads();
    for (int o = 1; o < 256; o <<= 1) {
        int n = (t >= o) ? sh[t - o] : 0;
        __syncthreads();
        sh[t] += n;
        __syncthreads();
    }
    if (t < SCAN_NBLOCKS) blockoff[t] = sh[t] - v;      // exclusive
    if (t == SCAN_NBLOCKS - 1) off[N_NODES] = sh[t];    // total
}

// writes off[i] AND cursor[i] = off[i]  (build_sorted then needs no off load)
__global__ void __launch_bounds__(256)
scan_final(const int* __restrict__ cnt, const int* __restrict__ blockoff,
           int* __restrict__ off, int* __restrict__ cursor) {
    int i = blockIdx.x * 256 + threadIdx.x;
    int lane = threadIdx.x & 63;
    int w    = threadIdx.x >> 6;
    int v = (i < N_NODES) ? cnt[i] : 0;
    int incl = v;
#pragma unroll
    for (int o = 1; o < 64; o <<= 1) {
        int n = __shfl_up(incl, o, 64);
        if (lane >= o) incl += n;
    }
    __shared__ int wsum[4];
    if (lane == 63) wsum[w] = incl;
    __syncthreads();
    int wofs = 0;
    for (int j = 0; j < w; ++j) wofs += wsum[j];
    if (i < N_NODES) {
        int e = incl - v + wofs + blockoff[blockIdx.x];
        off[i] = e;
        cursor[i] = e;
    }
}

// 4 edges/thread; cursor pre-initialized to off, so one atomic per edge.
__global__ void __launch_bounds__(256)
build_sorted(const int* __restrict__ src, const int* __restrict__ dst,
             int* __restrict__ cursor, int* __restrict__ sorted_src) {
    int i = blockIdx.x * 256 + threadIdx.x;
    if (i >= N_EDGES / 4) return;
    int4 s = ((const int4*)src)[i];
    int4 d = ((const int4*)dst)[i];
    sorted_src[atomicAdd(&cursor[d.x], 1)] = s.x;
    sorted_src[atomicAdd(&cursor[d.y], 1)] = s.y;
    sorted_src[atomicAdd(&cursor[d.z], 1)] = s.z;
    sorted_src[atomicAdd(&cursor[d.w], 1)] = s.w;
}

// One wave per node, 2 edges per instruction:
// half h = lane>>5 owns edge 2p+h; 32 lanes x float4 cover the 128-col row.
// Indices fetched coalesced 64-at-a-time, distributed by __shfl.
__global__ void __launch_bounds__(256)
gather_sum(const float* __restrict__ x,
           const int* __restrict__ sorted_src,
           const int* __restrict__ off,
           float* __restrict__ agg) {
    int node = (int)((blockIdx.x * 256 + threadIdx.x) >> 6);
    int lane = threadIdx.x & 63;
    if (node >= N_NODES) return;
    const int h  = lane >> 5;
    const int c4 = (lane & 31) << 2;
    const float* xb = x + c4;
    int beg = off[node], end = off[node + 1];

    float4 acc = make_float4(0.f, 0.f, 0.f, 0.f);
    for (int base = beg; base < end; base += 64) {
        int n = end - base;
        if (n > 64) n = 64;
        int idx = (lane < n) ? sorted_src[base + lane] : 0;   // coalesced
        int npairs = n >> 1;
        int p = 0;
        for (; p + 2 <= npairs; p += 2) {                     // 2 pairs in flight
            int sA = __shfl(idx, 2 * p + h, 64);
            int sB = __shfl(idx, 2 * p + 2 + h, 64);
            float4 vA = *(const float4*)(xb + (size_t)sA * D);
            float4 vB = *(const float4*)(xb + (size_t)sB * D);
            acc.x += vA.x + vB.x; acc.y += vA.y + vB.y;
            acc.z += vA.z + vB.z; acc.w += vA.w + vB.w;
        }
        for (; p < npairs; ++p) {
            int s = __shfl(idx, 2 * p + h, 64);
            float4 v = *(const float4*)(xb + (size_t)s * D);
            acc.x += v.x; acc.y += v.y; acc.z += v.z; acc.w += v.w;
        }
        if (n & 1) {
            int s = __shfl(idx, n - 1, 64);
            if (h == 0) {
                float4 v = *(const float4*)(xb + (size_t)s * D);
                acc.x += v.x; acc.y += v.y; acc.z += v.z; acc.w += v.w;
            }
        }
    }
    // merge halves: h=0 lanes get h=1 partials
    acc.x += __shfl_xor(acc.x, 32, 64);
    acc.y += __shfl_xor(acc.y, 32, 64);
    acc.z += __shfl_xor(acc.z, 32, 64);
    acc.w += __shfl_xor(acc.w, 32, 64);
    if (h == 0)
        *(float4*)(agg + (size_t)node * D + c4) = acc;
}

// ---------------------------------------------------------------------------
// MFMA GEMM, in place on d_out: data[n][o] = relu(sum_k agg[n][k]*W[o][k]) + x[n][o]
// Verified R5 tile: A[m=lane&15][k=q*8+j], B = W natural row-major => agg @ W.T,
// C/D: row = q*4+r, col = t*16 + m16. Block 256 = 4 waves x 16 rows = 64 rows.
// ---------------------------------------------------------------------------
__global__ void __launch_bounds__(256)
gemm_relu_res(float* data,                       // agg in / out out (in place)
              const float* __restrict__ W,
              const float* __restrict__ x) {
    __shared__ ushort Wl[128 * 128];        // 32 KB, chunk-major [k/8][o][8]
    __shared__ ushort Al[4 * 16 * 136];     // 17 KB, per-wave rows (stride 136)

    const int tid  = threadIdx.x;
    const int lane = tid & 63;
    const int wv   = tid >> 6;
    const int m16  = lane & 15;
    const int q    = lane >> 4;

    // stage W -> LDS (bf16, chunked): chunk g = kc*128 + o
#pragma unroll
    for (int i = 0; i < 8; ++i) {
        int g  = tid + i * 256;
        int o  = g & 127;
        int kc = g >> 7;
        const float4* wp = (const float4*)(W + (size_t)o * D + kc * 8);
        float4 w0 = wp[0], w1 = wp[1];
        bf16x8 hv;
        hv[0] = (short)f2bf(w0.x); hv[1] = (short)f2bf(w0.y);
        hv[2] = (short)f2bf(w0.z); hv[3] = (short)f2bf(w0.w);
        hv[4] = (short)f2bf(w1.x); hv[5] = (short)f2bf(w1.y);
        hv[6] = (short)f2bf(w1.z); hv[7] = (short)f2bf(w1.w);
        *(bf16x8*)&Wl[g * 8] = hv;
    }
    __syncthreads();

    const int nb = blockIdx.x * 64 + wv * 16;
    ushort* Aw = &Al[wv * (16 * 136)];

    // stage this wave's 16 agg rows (coalesced float2 per lane) -> bf16 LDS
#pragma unroll
    for (int m = 0; m < 16; ++m) {
        int node = nb + m;
        float2 v = make_float2(0.f, 0.f);
        if (node < N_NODES)
            v = *(const float2*)(data + (size_t)node * D + lane * 2);
        *(ushort2*)&Aw[m * 136 + lane * 2] = make_ushort2(f2bf(v.x), f2bf(v.y));
    }
    // same-wave LDS readback below — compiler inserts lgkmcnt, no barrier

    bf16x8 a[4];
#pragma unroll
    for (int kb = 0; kb < 4; ++kb)
        a[kb] = *(const bf16x8*)&Aw[m16 * 136 + kb * 32 + q * 8];

#pragma unroll
    for (int t = 0; t < 8; ++t) {
        f32x4 acc = {0.f, 0.f, 0.f, 0.f};
#pragma unroll
        for (int kb = 0; kb < 4; ++kb) {
            bf16x8 b = *(const bf16x8*)&Wl[(((kb * 4 + q) * 128) + t * 16 + m16) * 8];
            acc = __builtin_amdgcn_mfma_f32_16x16x32_bf16(a[kb], b, acc, 0, 0, 0);
        }
        const int col = t * 16 + m16;
        const int r0  = q * 4;
#pragma unroll
        for (int r = 0; r < 4; ++r) {
            int node = nb + r0 + r;
            if (node < N_NODES) {
                size_t idx = (size_t)node * D + col;
                data[idx] = fmaxf(acc[r], 0.f) + x[idx];
            }
        }
    }
}

extern "C" void kernel_launch(void* const* d_in, const int* in_sizes, int n_in,
                              void* d_out, int out_size, void* d_ws, size_t ws_size,
                              hipStream_t stream) {
    const float* x   = (const float*)d_in[0];
    const int*   src = (const int*)d_in[1];   // harness passes integers as int32
    const int*   dst = (const int*)d_in[2];
    const float* W   = (const float*)d_in[3];
    float* out = (float*)d_out;

    char* ws = (char*)d_ws;
    int* cnt        = (int*)ws;   ws += (size_t)N_NODES * 4;
    int* off        = (int*)ws;   ws += (size_t)(N_NODES + 1) * 4;
    int* cursor     = (int*)ws;   ws += (size_t)N_NODES * 4;
    int* blockoff   = (int*)ws;   ws += (size_t)SCAN_NBLOCKS * 4;
    int* sorted_src = (int*)ws;

    hipMemsetAsync(cnt, 0, (size_t)N_NODES * 4, stream);   // capturable (R2)

    histogram<<<(N_EDGES / 4 + 255) / 256, 256, 0, stream>>>(dst, cnt);
    scan_reduce<<<SCAN_NBLOCKS, 256, 0, stream>>>(cnt, blockoff /*blocksum*/);
    scan_partials<<<1, 256, 0, stream>>>(blockoff, blockoff, off);  // 1 block: in-place safe
    scan_final<<<SCAN_NBLOCKS, 256, 0, stream>>>(cnt, blockoff, off, cursor);
    build_sorted<<<(N_EDGES / 4 + 255) / 256, 256, 0, stream>>>(src, dst, cursor, sorted_src);

    long long n_gather = (long long)N_NODES * 64;
    gather_sum<<<(int)((n_gather + 255) / 256), 256, 0, stream>>>(x, sorted_src, off, out);

    gemm_relu_res<<<(N_NODES + 63) / 64, 256, 0, stream>>>(out, W, x);
}

// Round 7
// 232.405 us; speedup vs baseline: 1.3053x; 1.0913x over previous
//
#include <hip/hip_runtime.h>
#include <hip/hip_bf16.h>

#define N_NODES 50000
#define N_EDGES 800000
#define D 128

#define SCAN_NBLOCKS ((N_NODES + 255) / 256)   // 196

using bf16x8 = __attribute__((ext_vector_type(8))) short;   // 8 bf16 (4 VGPRs)
using f32x4  = __attribute__((ext_vector_type(4))) float;   // MFMA C/D

static __device__ __forceinline__ ushort f2bf(float f) {
    __hip_bfloat16 h = __float2bfloat16(f);   // RNE
    return *reinterpret_cast<ushort*>(&h);
}
static __device__ __forceinline__ float bf2f(ushort u) {
    unsigned v = ((unsigned)u) << 16;
    return __uint_as_float(v);
}

// ---------------------------------------------------------------------------
// ws layout: cnt[N], off[N+1], cursor[N], blockoff[196], sorted_src[E] (~3.8MB)
//            then (if room) xb = bf16 copy of x (12.8 MB).
// d_out: gather writes fp32 agg rows; gemm transforms rows in place
// (per-block row ownership is disjoint; in-block agg reads all precede
// epilogue stores via __syncthreads).
// ---------------------------------------------------------------------------

// Converts x -> bf16 AND zeroes cnt (folds the memset dispatch away).
__global__ void __launch_bounds__(256)
x_to_bf16(const float4* __restrict__ x4, ushort* __restrict__ xb,
          int* __restrict__ cnt) {
    int i = blockIdx.x * 256 + threadIdx.x;      // grid covers 1.6M >= N_NODES
    if (i < N_NODES) cnt[i] = 0;
    if (i >= N_NODES * D / 4) return;
    float4 v = x4[i];
    ushort4 u = make_ushort4(f2bf(v.x), f2bf(v.y), f2bf(v.z), f2bf(v.w));
    *(ushort4*)(xb + (size_t)i * 4) = u;
}

// 4 edges/thread, int4 loads.
__global__ void __launch_bounds__(256)
histogram(const int* __restrict__ dst, int* __restrict__ cnt) {
    int i = blockIdx.x * 256 + threadIdx.x;
    if (i >= N_EDGES / 4) return;
    int4 d = ((const int4*)dst)[i];
    atomicAdd(&cnt[d.x], 1);
    atomicAdd(&cnt[d.y], 1);
    atomicAdd(&cnt[d.z], 1);
    atomicAdd(&cnt[d.w], 1);
}

// 3-phase parallel exclusive scan (R3)
__global__ void __launch_bounds__(256)
scan_reduce(const int* __restrict__ cnt, int* __restrict__ blocksum) {
    int i = blockIdx.x * 256 + threadIdx.x;
    int v = (i < N_NODES) ? cnt[i] : 0;
#pragma unroll
    for (int o = 32; o; o >>= 1) v += __shfl_down(v, o, 64);
    __shared__ int ws_[4];
    if ((threadIdx.x & 63) == 0) ws_[threadIdx.x >> 6] = v;
    __syncthreads();
    if (threadIdx.x == 0)
        blocksum[blockIdx.x] = ws_[0] + ws_[1] + ws_[2] + ws_[3];
}

__global__ void __launch_bounds__(256)
scan_partials(const int* __restrict__ blocksum, int* __restrict__ blockoff,
              int* __restrict__ off) {
    __shared__ int sh[256];
    int t = threadIdx.x;
    int v = (t < SCAN_NBLOCKS) ? blocksum[t] : 0;
    sh[t] = v;
    __syncthreads();
    for (int o = 1; o < 256; o <<= 1) {
        int n = (t >= o) ? sh[t - o] : 0;
        __syncthreads();
        sh[t] += n;
        __syncthreads();
    }
    if (t < SCAN_NBLOCKS) blockoff[t] = sh[t] - v;      // exclusive
    if (t == SCAN_NBLOCKS - 1) off[N_NODES] = sh[t];    // total
}

__global__ void __launch_bounds__(256)
scan_final(const int* __restrict__ cnt, const int* __restrict__ blockoff,
           int* __restrict__ off, int* __restrict__ cursor) {
    int i = blockIdx.x * 256 + threadIdx.x;
    int lane = threadIdx.x & 63;
    int w    = threadIdx.x >> 6;
    int v = (i < N_NODES) ? cnt[i] : 0;
    int incl = v;
#pragma unroll
    for (int o = 1; o < 64; o <<= 1) {
        int n = __shfl_up(incl, o, 64);
        if (lane >= o) incl += n;
    }
    __shared__ int wsum[4];
    if (lane == 63) wsum[w] = incl;
    __syncthreads();
    int wofs = 0;
    for (int j = 0; j < w; ++j) wofs += wsum[j];
    if (i < N_NODES) {
        int e = incl - v + wofs + blockoff[blockIdx.x];
        off[i] = e;
        cursor[i] = e;
    }
}

__global__ void __launch_bounds__(256)
build_sorted(const int* __restrict__ src, const int* __restrict__ dst,
             int* __restrict__ cursor, int* __restrict__ sorted_src) {
    int i = blockIdx.x * 256 + threadIdx.x;
    if (i >= N_EDGES / 4) return;
    int4 s = ((const int4*)src)[i];
    int4 d = ((const int4*)dst)[i];
    sorted_src[atomicAdd(&cursor[d.x], 1)] = s.x;
    sorted_src[atomicAdd(&cursor[d.y], 1)] = s.y;
    sorted_src[atomicAdd(&cursor[d.z], 1)] = s.z;
    sorted_src[atomicAdd(&cursor[d.w], 1)] = s.w;
}

// bf16 gather: one wave per node, 2 edges per instruction (h = lane>>5),
// 32 lanes x ushort4 (8B) cover the 128-col bf16 row; fp32 accumulate.
__global__ void __launch_bounds__(256)
gather_sum_bf16(const ushort* __restrict__ xb,
                const int* __restrict__ sorted_src,
                const int* __restrict__ off,
                float* __restrict__ agg) {
    int node = (int)((blockIdx.x * 256 + threadIdx.x) >> 6);
    int lane = threadIdx.x & 63;
    if (node >= N_NODES) return;
    const int h = lane >> 5;
    const int c = (lane & 31) << 2;          // bf16 col 0..124
    const ushort* xbb = xb + c;
    int beg = off[node], end = off[node + 1];

    float4 acc = make_float4(0.f, 0.f, 0.f, 0.f);
    for (int base = beg; base < end; base += 64) {
        int n = end - base;
        if (n > 64) n = 64;
        int idx = (lane < n) ? sorted_src[base + lane] : 0;   // coalesced
        int npairs = n >> 1;
        int p = 0;
        for (; p + 4 <= npairs; p += 4) {                     // 4 rows in flight
            int s0 = __shfl(idx, 2 * p + h, 64);
            int s1 = __shfl(idx, 2 * p + 2 + h, 64);
            int s2 = __shfl(idx, 2 * p + 4 + h, 64);
            int s3 = __shfl(idx, 2 * p + 6 + h, 64);
            ushort4 u0 = *(const ushort4*)(xbb + (size_t)s0 * D);
            ushort4 u1 = *(const ushort4*)(xbb + (size_t)s1 * D);
            ushort4 u2 = *(const ushort4*)(xbb + (size_t)s2 * D);
            ushort4 u3 = *(const ushort4*)(xbb + (size_t)s3 * D);
            acc.x += (bf2f(u0.x) + bf2f(u1.x)) + (bf2f(u2.x) + bf2f(u3.x));
            acc.y += (bf2f(u0.y) + bf2f(u1.y)) + (bf2f(u2.y) + bf2f(u3.y));
            acc.z += (bf2f(u0.z) + bf2f(u1.z)) + (bf2f(u2.z) + bf2f(u3.z));
            acc.w += (bf2f(u0.w) + bf2f(u1.w)) + (bf2f(u2.w) + bf2f(u3.w));
        }
        for (; p < npairs; ++p) {
            int s = __shfl(idx, 2 * p + h, 64);
            ushort4 u = *(const ushort4*)(xbb + (size_t)s * D);
            acc.x += bf2f(u.x); acc.y += bf2f(u.y);
            acc.z += bf2f(u.z); acc.w += bf2f(u.w);
        }
        if (n & 1) {
            int s = __shfl(idx, n - 1, 64);
            if (h == 0) {
                ushort4 u = *(const ushort4*)(xbb + (size_t)s * D);
                acc.x += bf2f(u.x); acc.y += bf2f(u.y);
                acc.z += bf2f(u.z); acc.w += bf2f(u.w);
            }
        }
    }
    acc.x += __shfl_xor(acc.x, 32, 64);
    acc.y += __shfl_xor(acc.y, 32, 64);
    acc.z += __shfl_xor(acc.z, 32, 64);
    acc.w += __shfl_xor(acc.w, 32, 64);
    if (h == 0) {
        float4 v = make_float4(acc.x, acc.y, acc.z, acc.w);
        *(float4*)(agg + (size_t)node * D + (lane << 2)) = v;
    }
}

// fp32 fallback gather (R6, proven) — used only if ws can't hold xb.
__global__ void __launch_bounds__(256)
gather_sum_f32(const float* __restrict__ x,
               const int* __restrict__ sorted_src,
               const int* __restrict__ off,
               float* __restrict__ agg) {
    int node = (int)((blockIdx.x * 256 + threadIdx.x) >> 6);
    int lane = threadIdx.x & 63;
    if (node >= N_NODES) return;
    const int h  = lane >> 5;
    const int c4 = (lane & 31) << 2;
    const float* xbp = x + c4;
    int beg = off[node], end = off[node + 1];
    float4 acc = make_float4(0.f, 0.f, 0.f, 0.f);
    for (int base = beg; base < end; base += 64) {
        int n = end - base;
        if (n > 64) n = 64;
        int idx = (lane < n) ? sorted_src[base + lane] : 0;
        int npairs = n >> 1;
        int p = 0;
        for (; p + 2 <= npairs; p += 2) {
            int sA = __shfl(idx, 2 * p + h, 64);
            int sB = __shfl(idx, 2 * p + 2 + h, 64);
            float4 vA = *(const float4*)(xbp + (size_t)sA * D);
            float4 vB = *(const float4*)(xbp + (size_t)sB * D);
            acc.x += vA.x + vB.x; acc.y += vA.y + vB.y;
            acc.z += vA.z + vB.z; acc.w += vA.w + vB.w;
        }
        for (; p < npairs; ++p) {
            int s = __shfl(idx, 2 * p + h, 64);
            float4 v = *(const float4*)(xbp + (size_t)s * D);
            acc.x += v.x; acc.y += v.y; acc.z += v.z; acc.w += v.w;
        }
        if (n & 1) {
            int s = __shfl(idx, n - 1, 64);
            if (h == 0) {
                float4 v = *(const float4*)(xbp + (size_t)s * D);
                acc.x += v.x; acc.y += v.y; acc.z += v.z; acc.w += v.w;
            }
        }
    }
    acc.x += __shfl_xor(acc.x, 32, 64);
    acc.y += __shfl_xor(acc.y, 32, 64);
    acc.z += __shfl_xor(acc.z, 32, 64);
    acc.w += __shfl_xor(acc.w, 32, 64);
    if (h == 0)
        *(float4*)(agg + (size_t)node * D + c4) = acc;
}

// ---------------------------------------------------------------------------
// MFMA GEMM, in place on d_out. Verified R5/R6 tile. New: LDS-transposed
// epilogue -> coalesced float4 x-loads and out-stores.
// LDS phases:  [Wl 32KB | Al 17KB]  ->  (sync)  ->  [Ep 33.8KB overlay]
// ---------------------------------------------------------------------------
__global__ void __launch_bounds__(256)
gemm_relu_res(float* data,                       // agg in / out out (in place)
              const float* __restrict__ W,
              const float* __restrict__ x) {
    __shared__ __align__(16) char lds[50176];
    ushort* Wl = (ushort*)lds;                   // [0, 32768): chunk-major W
    ushort* Al = (ushort*)(lds + 32768);         // [32768, 50176): A rows

    const int tid  = threadIdx.x;
    const int lane = tid & 63;
    const int wv   = tid >> 6;
    const int m16  = lane & 15;
    const int q    = lane >> 4;

    // stage W -> LDS (bf16, chunked): chunk g = kc*128 + o
#pragma unroll
    for (int i = 0; i < 8; ++i) {
        int g  = tid + i * 256;
        int o  = g & 127;
        int kc = g >> 7;
        const float4* wp = (const float4*)(W + (size_t)o * D + kc * 8);
        float4 w0 = wp[0], w1 = wp[1];
        bf16x8 hv;
        hv[0] = (short)f2bf(w0.x); hv[1] = (short)f2bf(w0.y);
        hv[2] = (short)f2bf(w0.z); hv[3] = (short)f2bf(w0.w);
        hv[4] = (short)f2bf(w1.x); hv[5] = (short)f2bf(w1.y);
        hv[6] = (short)f2bf(w1.z); hv[7] = (short)f2bf(w1.w);
        *(bf16x8*)&Wl[g * 8] = hv;
    }
    __syncthreads();

    const int nb = blockIdx.x * 64 + wv * 16;
    ushort* Aw = &Al[wv * (16 * 136)];

    // stage this wave's 16 agg rows (coalesced float2/lane) -> bf16 LDS
#pragma unroll
    for (int m = 0; m < 16; ++m) {
        int node = nb + m;
        float2 v = make_float2(0.f, 0.f);
        if (node < N_NODES)
            v = *(const float2*)(data + (size_t)node * D + lane * 2);
        *(ushort2*)&Aw[m * 136 + lane * 2] = make_ushort2(f2bf(v.x), f2bf(v.y));
    }
    // same-wave readback: compiler inserts lgkmcnt, no barrier needed

    bf16x8 a[4];
#pragma unroll
    for (int kb = 0; kb < 4; ++kb)
        a[kb] = *(const bf16x8*)&Aw[m16 * 136 + kb * 32 + q * 8];

    f32x4 acc[8];
#pragma unroll
    for (int t = 0; t < 8; ++t) {
        acc[t] = (f32x4){0.f, 0.f, 0.f, 0.f};
#pragma unroll
        for (int kb = 0; kb < 4; ++kb) {
            bf16x8 b = *(const bf16x8*)&Wl[(((kb * 4 + q) * 128) + t * 16 + m16) * 8];
            acc[t] = __builtin_amdgcn_mfma_f32_16x16x32_bf16(a[kb], b, acc[t], 0, 0, 0);
        }
    }

    // ---- epilogue: LDS transpose -> coalesced stores ----
    __syncthreads();                              // Wl/Al dead after this
    float* Ew = (float*)(lds + wv * 8448);        // 16 rows x 132 floats
#pragma unroll
    for (int t = 0; t < 8; ++t)
#pragma unroll
        for (int r = 0; r < 4; ++r)
            Ew[(q * 4 + r) * 132 + t * 16 + m16] = acc[t][r];
    // same-wave readback below

    const int h  = lane >> 5;
    const int c4 = (lane & 31) << 2;
#pragma unroll
    for (int j = 0; j < 8; ++j) {
        int r = j * 2 + h;
        int node = nb + r;
        if (node < N_NODES) {
            float4 v  = *(const float4*)&Ew[r * 132 + c4];
            float4 xi = *(const float4*)(x + (size_t)node * D + c4);
            float4 o;
            o.x = fmaxf(v.x, 0.f) + xi.x;
            o.y = fmaxf(v.y, 0.f) + xi.y;
            o.z = fmaxf(v.z, 0.f) + xi.z;
            o.w = fmaxf(v.w, 0.f) + xi.w;
            *(float4*)(data + (size_t)node * D + c4) = o;
        }
    }
}

extern "C" void kernel_launch(void* const* d_in, const int* in_sizes, int n_in,
                              void* d_out, int out_size, void* d_ws, size_t ws_size,
                              hipStream_t stream) {
    const float* x   = (const float*)d_in[0];
    const int*   src = (const int*)d_in[1];   // harness passes integers as int32
    const int*   dst = (const int*)d_in[2];
    const float* W   = (const float*)d_in[3];
    float* out = (float*)d_out;

    char* ws = (char*)d_ws;
    int* cnt        = (int*)ws;   ws += (size_t)N_NODES * 4;
    int* off        = (int*)ws;   ws += (size_t)(N_NODES + 1) * 4;
    int* cursor     = (int*)ws;   ws += (size_t)N_NODES * 4;
    int* blockoff   = (int*)ws;   ws += (size_t)SCAN_NBLOCKS * 4;
    int* sorted_src = (int*)ws;   ws += (size_t)N_EDGES * 4;
    ws = (char*)(((uintptr_t)ws + 15) & ~(uintptr_t)15);
    ushort* xb      = (ushort*)ws;
    const size_t need = (size_t)(ws - (char*)d_ws) + (size_t)N_NODES * D * 2;
    const bool bf16_path = (ws_size >= need);

    if (bf16_path) {
        x_to_bf16<<<(N_NODES * D / 4 + 255) / 256, 256, 0, stream>>>(
            (const float4*)x, xb, cnt);
    } else {
        hipMemsetAsync(cnt, 0, (size_t)N_NODES * 4, stream);
    }

    histogram<<<(N_EDGES / 4 + 255) / 256, 256, 0, stream>>>(dst, cnt);
    scan_reduce<<<SCAN_NBLOCKS, 256, 0, stream>>>(cnt, blockoff /*blocksum*/);
    scan_partials<<<1, 256, 0, stream>>>(blockoff, blockoff, off);  // 1 block: safe
    scan_final<<<SCAN_NBLOCKS, 256, 0, stream>>>(cnt, blockoff, off, cursor);
    build_sorted<<<(N_EDGES / 4 + 255) / 256, 256, 0, stream>>>(src, dst, cursor, sorted_src);

    long long n_gather = (long long)N_NODES * 64;
    int gblocks = (int)((n_gather + 255) / 256);
    if (bf16_path)
        gather_sum_bf16<<<gblocks, 256, 0, stream>>>(xb, sorted_src, off, out);
    else
        gather_sum_f32<<<gblocks, 256, 0, stream>>>(x, sorted_src, off, out);

    gemm_relu_res<<<(N_NODES + 63) / 64, 256, 0, stream>>>(out, W, x);
}

// Round 8
// 221.165 us; speedup vs baseline: 1.3717x; 1.0508x over previous
//
#include <hip/hip_runtime.h>
#include <hip/hip_bf16.h>

#define N_NODES 50000
#define N_EDGES 800000
#define D 128

#define SCAN_NBLOCKS ((N_NODES + 255) / 256)   // 196
#define NBUCK SCAN_NBLOCKS                      // bucket b = nodes [b*256,(b+1)*256)

using bf16x8 = __attribute__((ext_vector_type(8))) short;   // 8 bf16 (4 VGPRs)
using f32x4  = __attribute__((ext_vector_type(4))) float;   // MFMA C/D

static __device__ __forceinline__ ushort f2bf(float f) {
    __hip_bfloat16 h = __float2bfloat16(f);   // RNE
    return *reinterpret_cast<ushort*>(&h);
}
static __device__ __forceinline__ float bf2f(ushort u) {
    unsigned v = ((unsigned)u) << 16;
    return __uint_as_float(v);
}

// ---------------------------------------------------------------------------
// ws layout: cnt[N], off[N+1], cursor[N], blockoff[196], bcursor[196],
//            sorted_src[E], pairs[E] (int2), xb (bf16 x copy).
// Free facts: blocksum[b] = bucket b's edge count; blockoff[b] = off[b*256]
// = bucket b's base in both sorted_src (x4B) and pairs (x8B).
// ---------------------------------------------------------------------------

// Converts x -> bf16 AND zeroes cnt (folds the memset dispatch away).
__global__ void __launch_bounds__(256)
x_to_bf16(const float4* __restrict__ x4, ushort* __restrict__ xb,
          int* __restrict__ cnt) {
    int i = blockIdx.x * 256 + threadIdx.x;
    if (i < N_NODES) cnt[i] = 0;
    if (i >= N_NODES * D / 4) return;
    float4 v = x4[i];
    ushort4 u = make_ushort4(f2bf(v.x), f2bf(v.y), f2bf(v.z), f2bf(v.w));
    *(ushort4*)(xb + (size_t)i * 4) = u;
}

// 4 edges/thread, int4 loads.
__global__ void __launch_bounds__(256)
histogram(const int* __restrict__ dst, int* __restrict__ cnt) {
    int i = blockIdx.x * 256 + threadIdx.x;
    if (i >= N_EDGES / 4) return;
    int4 d = ((const int4*)dst)[i];
    atomicAdd(&cnt[d.x], 1);
    atomicAdd(&cnt[d.y], 1);
    atomicAdd(&cnt[d.z], 1);
    atomicAdd(&cnt[d.w], 1);
}

// 3-phase parallel exclusive scan (R3)
__global__ void __launch_bounds__(256)
scan_reduce(const int* __restrict__ cnt, int* __restrict__ blocksum) {
    int i = blockIdx.x * 256 + threadIdx.x;
    int v = (i < N_NODES) ? cnt[i] : 0;
#pragma unroll
    for (int o = 32; o; o >>= 1) v += __shfl_down(v, o, 64);
    __shared__ int ws_[4];
    if ((threadIdx.x & 63) == 0) ws_[threadIdx.x >> 6] = v;
    __syncthreads();
    if (threadIdx.x == 0)
        blocksum[blockIdx.x] = ws_[0] + ws_[1] + ws_[2] + ws_[3];
}

// also emits bcursor[b] = exclusive bucket base (for bucket_scatter)
__global__ void __launch_bounds__(256)
scan_partials(const int* __restrict__ blocksum, int* __restrict__ blockoff,
              int* __restrict__ bcursor, int* __restrict__ off) {
    __shared__ int sh[256];
    int t = threadIdx.x;
    int v = (t < SCAN_NBLOCKS) ? blocksum[t] : 0;
    sh[t] = v;
    __syncthreads();
    for (int o = 1; o < 256; o <<= 1) {
        int n = (t >= o) ? sh[t - o] : 0;
        __syncthreads();
        sh[t] += n;
        __syncthreads();
    }
    if (t < SCAN_NBLOCKS) {
        int e = sh[t] - v;            // exclusive
        blockoff[t] = e;
        bcursor[t]  = e;
    }
    if (t == SCAN_NBLOCKS - 1) off[N_NODES] = sh[t];    // total
}

__global__ void __launch_bounds__(256)
scan_final(const int* __restrict__ cnt, const int* __restrict__ blockoff,
           int* __restrict__ off, int* __restrict__ cursor) {
    int i = blockIdx.x * 256 + threadIdx.x;
    int lane = threadIdx.x & 63;
    int w    = threadIdx.x >> 6;
    int v = (i < N_NODES) ? cnt[i] : 0;
    int incl = v;
#pragma unroll
    for (int o = 1; o < 64; o <<= 1) {
        int n = __shfl_up(incl, o, 64);
        if (lane >= o) incl += n;
    }
    __shared__ int wsum[4];
    if (lane == 63) wsum[w] = incl;
    __syncthreads();
    int wofs = 0;
    for (int j = 0; j < w; ++j) wofs += wsum[j];
    if (i < N_NODES) {
        int e = incl - v + wofs + blockoff[blockIdx.x];
        off[i] = e;
        cursor[i] = e;
    }
}

// ---------------------------------------------------------------------------
// Bucketed CSR build (replaces the 44us cross-XCD-thrashing build_sorted):
// Stage 1: cluster edges into 196 dst-buckets; all writes to a bucket window
//          from one block (LDS-aggregated reservations).
// Stage 2: one block per bucket scatters into its 16KB CSR window.
// ---------------------------------------------------------------------------
__global__ void __launch_bounds__(1024)
bucket_scatter(const int* __restrict__ src, const int* __restrict__ dst,
               int* __restrict__ bcursor, int2* __restrict__ pairs) {
    __shared__ int lcnt[NBUCK], lbase[NBUCK];
    const int tid = threadIdx.x;
    if (tid < NBUCK) lcnt[tid] = 0;
    __syncthreads();

    const int i = blockIdx.x * 1024 + tid;
    const bool valid = i < N_EDGES / 4;
    int4 s, d;
    int bkt[4], slot[4];
    if (valid) {
        s = ((const int4*)src)[i];
        d = ((const int4*)dst)[i];
        bkt[0] = d.x >> 8; slot[0] = atomicAdd(&lcnt[bkt[0]], 1);
        bkt[1] = d.y >> 8; slot[1] = atomicAdd(&lcnt[bkt[1]], 1);
        bkt[2] = d.z >> 8; slot[2] = atomicAdd(&lcnt[bkt[2]], 1);
        bkt[3] = d.w >> 8; slot[3] = atomicAdd(&lcnt[bkt[3]], 1);
    }
    __syncthreads();
    if (tid < NBUCK) {
        int c = lcnt[tid];
        lbase[tid] = c ? atomicAdd(&bcursor[tid], c) : 0;
    }
    __syncthreads();
    if (valid) {
        pairs[lbase[bkt[0]] + slot[0]] = make_int2(s.x, d.x);
        pairs[lbase[bkt[1]] + slot[1]] = make_int2(s.y, d.y);
        pairs[lbase[bkt[2]] + slot[2]] = make_int2(s.z, d.z);
        pairs[lbase[bkt[3]] + slot[3]] = make_int2(s.w, d.w);
    }
}

__global__ void __launch_bounds__(256)
bucket_to_csr(const int2* __restrict__ pairs, const int* __restrict__ blockoff,
              int* __restrict__ cursor, int* __restrict__ sorted_src) {
    const int b   = blockIdx.x;
    const int beg = blockoff[b];
    const int end = (b == NBUCK - 1) ? N_EDGES : blockoff[b + 1];
    for (int i = beg + threadIdx.x; i < end; i += 256) {
        int2 p = pairs[i];
        int pos = atomicAdd(&cursor[p.y], 1);
        sorted_src[pos] = p.x;
    }
}

// fallback (R6 path) if ws too small for pairs+xb
__global__ void __launch_bounds__(256)
build_sorted(const int* __restrict__ src, const int* __restrict__ dst,
             int* __restrict__ cursor, int* __restrict__ sorted_src) {
    int i = blockIdx.x * 256 + threadIdx.x;
    if (i >= N_EDGES / 4) return;
    int4 s = ((const int4*)src)[i];
    int4 d = ((const int4*)dst)[i];
    sorted_src[atomicAdd(&cursor[d.x], 1)] = s.x;
    sorted_src[atomicAdd(&cursor[d.y], 1)] = s.y;
    sorted_src[atomicAdd(&cursor[d.z], 1)] = s.z;
    sorted_src[atomicAdd(&cursor[d.w], 1)] = s.w;
}

// bf16 gather: one wave per node, 2 edges per instruction (h = lane>>5),
// 32 lanes x ushort4 (8B) cover the 128-col bf16 row; fp32 accumulate.
__global__ void __launch_bounds__(256)
gather_sum_bf16(const ushort* __restrict__ xb,
                const int* __restrict__ sorted_src,
                const int* __restrict__ off,
                float* __restrict__ agg) {
    int node = (int)((blockIdx.x * 256 + threadIdx.x) >> 6);
    int lane = threadIdx.x & 63;
    if (node >= N_NODES) return;
    const int h = lane >> 5;
    const int c = (lane & 31) << 2;
    const ushort* xbb = xb + c;
    int beg = off[node], end = off[node + 1];

    float4 acc = make_float4(0.f, 0.f, 0.f, 0.f);
    for (int base = beg; base < end; base += 64) {
        int n = end - base;
        if (n > 64) n = 64;
        int idx = (lane < n) ? sorted_src[base + lane] : 0;
        int npairs = n >> 1;
        int p = 0;
        for (; p + 4 <= npairs; p += 4) {
            int s0 = __shfl(idx, 2 * p + h, 64);
            int s1 = __shfl(idx, 2 * p + 2 + h, 64);
            int s2 = __shfl(idx, 2 * p + 4 + h, 64);
            int s3 = __shfl(idx, 2 * p + 6 + h, 64);
            ushort4 u0 = *(const ushort4*)(xbb + (size_t)s0 * D);
            ushort4 u1 = *(const ushort4*)(xbb + (size_t)s1 * D);
            ushort4 u2 = *(const ushort4*)(xbb + (size_t)s2 * D);
            ushort4 u3 = *(const ushort4*)(xbb + (size_t)s3 * D);
            acc.x += (bf2f(u0.x) + bf2f(u1.x)) + (bf2f(u2.x) + bf2f(u3.x));
            acc.y += (bf2f(u0.y) + bf2f(u1.y)) + (bf2f(u2.y) + bf2f(u3.y));
            acc.z += (bf2f(u0.z) + bf2f(u1.z)) + (bf2f(u2.z) + bf2f(u3.z));
            acc.w += (bf2f(u0.w) + bf2f(u1.w)) + (bf2f(u2.w) + bf2f(u3.w));
        }
        for (; p < npairs; ++p) {
            int s = __shfl(idx, 2 * p + h, 64);
            ushort4 u = *(const ushort4*)(xbb + (size_t)s * D);
            acc.x += bf2f(u.x); acc.y += bf2f(u.y);
            acc.z += bf2f(u.z); acc.w += bf2f(u.w);
        }
        if (n & 1) {
            int s = __shfl(idx, n - 1, 64);
            if (h == 0) {
                ushort4 u = *(const ushort4*)(xbb + (size_t)s * D);
                acc.x += bf2f(u.x); acc.y += bf2f(u.y);
                acc.z += bf2f(u.z); acc.w += bf2f(u.w);
            }
        }
    }
    acc.x += __shfl_xor(acc.x, 32, 64);
    acc.y += __shfl_xor(acc.y, 32, 64);
    acc.z += __shfl_xor(acc.z, 32, 64);
    acc.w += __shfl_xor(acc.w, 32, 64);
    if (h == 0) {
        float4 v = make_float4(acc.x, acc.y, acc.z, acc.w);
        *(float4*)(agg + (size_t)node * D + (lane << 2)) = v;
    }
}

// fp32 fallback gather (R6, proven)
__global__ void __launch_bounds__(256)
gather_sum_f32(const float* __restrict__ x,
               const int* __restrict__ sorted_src,
               const int* __restrict__ off,
               float* __restrict__ agg) {
    int node = (int)((blockIdx.x * 256 + threadIdx.x) >> 6);
    int lane = threadIdx.x & 63;
    if (node >= N_NODES) return;
    const int h  = lane >> 5;
    const int c4 = (lane & 31) << 2;
    const float* xbp = x + c4;
    int beg = off[node], end = off[node + 1];
    float4 acc = make_float4(0.f, 0.f, 0.f, 0.f);
    for (int base = beg; base < end; base += 64) {
        int n = end - base;
        if (n > 64) n = 64;
        int idx = (lane < n) ? sorted_src[base + lane] : 0;
        int npairs = n >> 1;
        int p = 0;
        for (; p + 2 <= npairs; p += 2) {
            int sA = __shfl(idx, 2 * p + h, 64);
            int sB = __shfl(idx, 2 * p + 2 + h, 64);
            float4 vA = *(const float4*)(xbp + (size_t)sA * D);
            float4 vB = *(const float4*)(xbp + (size_t)sB * D);
            acc.x += vA.x + vB.x; acc.y += vA.y + vB.y;
            acc.z += vA.z + vB.z; acc.w += vA.w + vB.w;
        }
        for (; p < npairs; ++p) {
            int s = __shfl(idx, 2 * p + h, 64);
            float4 v = *(const float4*)(xbp + (size_t)s * D);
            acc.x += v.x; acc.y += v.y; acc.z += v.z; acc.w += v.w;
        }
        if (n & 1) {
            int s = __shfl(idx, n - 1, 64);
            if (h == 0) {
                float4 v = *(const float4*)(xbp + (size_t)s * D);
                acc.x += v.x; acc.y += v.y; acc.z += v.z; acc.w += v.w;
            }
        }
    }
    acc.x += __shfl_xor(acc.x, 32, 64);
    acc.y += __shfl_xor(acc.y, 32, 64);
    acc.z += __shfl_xor(acc.z, 32, 64);
    acc.w += __shfl_xor(acc.w, 32, 64);
    if (h == 0)
        *(float4*)(agg + (size_t)node * D + c4) = acc;
}

// ---------------------------------------------------------------------------
// MFMA GEMM, in place on d_out (verified R5-R7): LDS-transposed epilogue.
// ---------------------------------------------------------------------------
__global__ void __launch_bounds__(256)
gemm_relu_res(float* data,                       // agg in / out out (in place)
              const float* __restrict__ W,
              const float* __restrict__ x) {
    __shared__ __align__(16) char lds[50176];
    ushort* Wl = (ushort*)lds;                   // [0, 32768): chunk-major W
    ushort* Al = (ushort*)(lds + 32768);         // [32768, 50176): A rows

    const int tid  = threadIdx.x;
    const int lane = tid & 63;
    const int wv   = tid >> 6;
    const int m16  = lane & 15;
    const int q    = lane >> 4;

#pragma unroll
    for (int i = 0; i < 8; ++i) {
        int g  = tid + i * 256;
        int o  = g & 127;
        int kc = g >> 7;
        const float4* wp = (const float4*)(W + (size_t)o * D + kc * 8);
        float4 w0 = wp[0], w1 = wp[1];
        bf16x8 hv;
        hv[0] = (short)f2bf(w0.x); hv[1] = (short)f2bf(w0.y);
        hv[2] = (short)f2bf(w0.z); hv[3] = (short)f2bf(w0.w);
        hv[4] = (short)f2bf(w1.x); hv[5] = (short)f2bf(w1.y);
        hv[6] = (short)f2bf(w1.z); hv[7] = (short)f2bf(w1.w);
        *(bf16x8*)&Wl[g * 8] = hv;
    }
    __syncthreads();

    const int nb = blockIdx.x * 64 + wv * 16;
    ushort* Aw = &Al[wv * (16 * 136)];

#pragma unroll
    for (int m = 0; m < 16; ++m) {
        int node = nb + m;
        float2 v = make_float2(0.f, 0.f);
        if (node < N_NODES)
            v = *(const float2*)(data + (size_t)node * D + lane * 2);
        *(ushort2*)&Aw[m * 136 + lane * 2] = make_ushort2(f2bf(v.x), f2bf(v.y));
    }

    bf16x8 a[4];
#pragma unroll
    for (int kb = 0; kb < 4; ++kb)
        a[kb] = *(const bf16x8*)&Aw[m16 * 136 + kb * 32 + q * 8];

    f32x4 acc[8];
#pragma unroll
    for (int t = 0; t < 8; ++t) {
        acc[t] = (f32x4){0.f, 0.f, 0.f, 0.f};
#pragma unroll
        for (int kb = 0; kb < 4; ++kb) {
            bf16x8 b = *(const bf16x8*)&Wl[(((kb * 4 + q) * 128) + t * 16 + m16) * 8];
            acc[t] = __builtin_amdgcn_mfma_f32_16x16x32_bf16(a[kb], b, acc[t], 0, 0, 0);
        }
    }

    __syncthreads();                              // Wl/Al dead after this
    float* Ew = (float*)(lds + wv * 8448);        // 16 rows x 132 floats
#pragma unroll
    for (int t = 0; t < 8; ++t)
#pragma unroll
        for (int r = 0; r < 4; ++r)
            Ew[(q * 4 + r) * 132 + t * 16 + m16] = acc[t][r];

    const int h  = lane >> 5;
    const int c4 = (lane & 31) << 2;
#pragma unroll
    for (int j = 0; j < 8; ++j) {
        int r = j * 2 + h;
        int node = nb + r;
        if (node < N_NODES) {
            float4 v  = *(const float4*)&Ew[r * 132 + c4];
            float4 xi = *(const float4*)(x + (size_t)node * D + c4);
            float4 o;
            o.x = fmaxf(v.x, 0.f) + xi.x;
            o.y = fmaxf(v.y, 0.f) + xi.y;
            o.z = fmaxf(v.z, 0.f) + xi.z;
            o.w = fmaxf(v.w, 0.f) + xi.w;
            *(float4*)(data + (size_t)node * D + c4) = o;
        }
    }
}

extern "C" void kernel_launch(void* const* d_in, const int* in_sizes, int n_in,
                              void* d_out, int out_size, void* d_ws, size_t ws_size,
                              hipStream_t stream) {
    const float* x   = (const float*)d_in[0];
    const int*   src = (const int*)d_in[1];   // harness passes integers as int32
    const int*   dst = (const int*)d_in[2];
    const float* W   = (const float*)d_in[3];
    float* out = (float*)d_out;

    char* ws = (char*)d_ws;
    int* cnt        = (int*)ws;   ws += (size_t)N_NODES * 4;
    int* off        = (int*)ws;   ws += (size_t)(N_NODES + 1) * 4;
    int* cursor     = (int*)ws;   ws += (size_t)N_NODES * 4;
    int* blockoff   = (int*)ws;   ws += (size_t)SCAN_NBLOCKS * 4;
    int* bcursor    = (int*)ws;   ws += (size_t)NBUCK * 4;
    int* sorted_src = (int*)ws;   ws += (size_t)N_EDGES * 4;
    ws = (char*)(((uintptr_t)ws + 15) & ~(uintptr_t)15);
    int2* pairs     = (int2*)ws;  ws += (size_t)N_EDGES * 8;
    ushort* xb      = (ushort*)ws;
    const size_t need = (size_t)(ws - (char*)d_ws) + (size_t)N_NODES * D * 2;
    const bool big_ws = (ws_size >= need);   // bucketed build + bf16 gather

    if (big_ws) {
        x_to_bf16<<<(N_NODES * D / 4 + 255) / 256, 256, 0, stream>>>(
            (const float4*)x, xb, cnt);
    } else {
        hipMemsetAsync(cnt, 0, (size_t)N_NODES * 4, stream);
    }

    histogram<<<(N_EDGES / 4 + 255) / 256, 256, 0, stream>>>(dst, cnt);
    scan_reduce<<<SCAN_NBLOCKS, 256, 0, stream>>>(cnt, blockoff /*blocksum*/);
    scan_partials<<<1, 256, 0, stream>>>(blockoff, blockoff, bcursor, off);
    scan_final<<<SCAN_NBLOCKS, 256, 0, stream>>>(cnt, blockoff, off, cursor);

    if (big_ws) {
        bucket_scatter<<<(N_EDGES / 4 + 1023) / 1024, 1024, 0, stream>>>(
            src, dst, bcursor, pairs);
        bucket_to_csr<<<NBUCK, 256, 0, stream>>>(pairs, blockoff, cursor, sorted_src);
    } else {
        build_sorted<<<(N_EDGES / 4 + 255) / 256, 256, 0, stream>>>(
            src, dst, cursor, sorted_src);
    }

    long long n_gather = (long long)N_NODES * 64;
    int gblocks = (int)((n_gather + 255) / 256);
    if (big_ws)
        gather_sum_bf16<<<gblocks, 256, 0, stream>>>(xb, sorted_src, off, out);
    else
        gather_sum_f32<<<gblocks, 256, 0, stream>>>(x, sorted_src, off, out);

    gemm_relu_res<<<(N_NODES + 63) / 64, 256, 0, stream>>>(out, W, x);
}

// Round 9
// 199.646 us; speedup vs baseline: 1.5195x; 1.1078x over previous
//
#include <hip/hip_runtime.h>
#include <hip/hip_bf16.h>

#define N_NODES 50000
#define N_EDGES 800000
#define D 128

#define SCAN_NBLOCKS ((N_NODES + 255) / 256)   // 196
#define NBUCK SCAN_NBLOCKS                      // bucket b = nodes [b*256,(b+1)*256)
#define BCAP 6144                               // bucket edge capacity (mean 4096, sd 64)

using bf16x8 = __attribute__((ext_vector_type(8))) short;   // 8 bf16 (4 VGPRs)
using f32x4  = __attribute__((ext_vector_type(4))) float;   // MFMA C/D

static __device__ __forceinline__ ushort f2bf(float f) {
    __hip_bfloat16 h = __float2bfloat16(f);   // RNE
    return *reinterpret_cast<ushort*>(&h);
}
static __device__ __forceinline__ float bf2f(ushort u) {
    unsigned v = ((unsigned)u) << 16;
    return __uint_as_float(v);
}

// ---------------------------------------------------------------------------
// ws layout (main path, ~30 MB of 256 MB):
//   cnt[N], off[N+1], cursor[N] (fallback only), blockoff[196], bcursor[196],
//   pairs[E] (packed int: (dst&255)<<16 | src; src<2^16, local dst<2^8),
//   xb = bf16 x (12.8 MB), aggb = bf16 agg (12.8 MB).
// d_out written solely by the GEMM epilogue (all rows covered).
// ---------------------------------------------------------------------------

// Converts x -> bf16 AND zeroes cnt (folds the memset dispatch away).
__global__ void __launch_bounds__(256)
x_to_bf16(const float4* __restrict__ x4, ushort* __restrict__ xb,
          int* __restrict__ cnt) {
    int i = blockIdx.x * 256 + threadIdx.x;
    if (i < N_NODES) cnt[i] = 0;
    if (i >= N_NODES * D / 4) return;
    float4 v = x4[i];
    ushort4 u = make_ushort4(f2bf(v.x), f2bf(v.y), f2bf(v.z), f2bf(v.w));
    *(ushort4*)(xb + (size_t)i * 4) = u;
}

// 4 edges/thread, int4 loads.
__global__ void __launch_bounds__(256)
histogram(const int* __restrict__ dst, int* __restrict__ cnt) {
    int i = blockIdx.x * 256 + threadIdx.x;
    if (i >= N_EDGES / 4) return;
    int4 d = ((const int4*)dst)[i];
    atomicAdd(&cnt[d.x], 1);
    atomicAdd(&cnt[d.y], 1);
    atomicAdd(&cnt[d.z], 1);
    atomicAdd(&cnt[d.w], 1);
}

// 3-phase parallel exclusive scan (R3)
__global__ void __launch_bounds__(256)
scan_reduce(const int* __restrict__ cnt, int* __restrict__ blocksum) {
    int i = blockIdx.x * 256 + threadIdx.x;
    int v = (i < N_NODES) ? cnt[i] : 0;
#pragma unroll
    for (int o = 32; o; o >>= 1) v += __shfl_down(v, o, 64);
    __shared__ int ws_[4];
    if ((threadIdx.x & 63) == 0) ws_[threadIdx.x >> 6] = v;
    __syncthreads();
    if (threadIdx.x == 0)
        blocksum[blockIdx.x] = ws_[0] + ws_[1] + ws_[2] + ws_[3];
}

// emits blockoff (bucket CSR base) + bcursor (scatter cursor) + total
__global__ void __launch_bounds__(256)
scan_partials(const int* __restrict__ blocksum, int* __restrict__ blockoff,
              int* __restrict__ bcursor, int* __restrict__ off) {
    __shared__ int sh[256];
    int t = threadIdx.x;
    int v = (t < SCAN_NBLOCKS) ? blocksum[t] : 0;
    sh[t] = v;
    __syncthreads();
    for (int o = 1; o < 256; o <<= 1) {
        int n = (t >= o) ? sh[t - o] : 0;
        __syncthreads();
        sh[t] += n;
        __syncthreads();
    }
    if (t < SCAN_NBLOCKS) {
        int e = sh[t] - v;            // exclusive
        blockoff[t] = e;
        bcursor[t]  = e;
    }
    if (t == SCAN_NBLOCKS - 1) off[N_NODES] = sh[t];    // total
}

__global__ void __launch_bounds__(256)
scan_final(const int* __restrict__ cnt, const int* __restrict__ blockoff,
           int* __restrict__ off, int* __restrict__ cursor) {
    int i = blockIdx.x * 256 + threadIdx.x;
    int lane = threadIdx.x & 63;
    int w    = threadIdx.x >> 6;
    int v = (i < N_NODES) ? cnt[i] : 0;
    int incl = v;
#pragma unroll
    for (int o = 1; o < 64; o <<= 1) {
        int n = __shfl_up(incl, o, 64);
        if (lane >= o) incl += n;
    }
    __shared__ int wsum[4];
    if (lane == 63) wsum[w] = incl;
    __syncthreads();
    int wofs = 0;
    for (int j = 0; j < w; ++j) wofs += wsum[j];
    if (i < N_NODES) {
        int e = incl - v + wofs + blockoff[blockIdx.x];
        off[i] = e;
        cursor[i] = e;     // used by fallback build_sorted only
    }
}

// Stage 1: cluster edges into 196 dst-buckets (packed int), writes localized
// per block via LDS-aggregated reservations.
__global__ void __launch_bounds__(1024)
bucket_scatter(const int* __restrict__ src, const int* __restrict__ dst,
               int* __restrict__ bcursor, int* __restrict__ pairs) {
    __shared__ int lcnt[NBUCK], lbase[NBUCK];
    const int tid = threadIdx.x;
    if (tid < NBUCK) lcnt[tid] = 0;
    __syncthreads();

    const int i = blockIdx.x * 1024 + tid;
    const bool valid = i < N_EDGES / 4;
    int4 s, d;
    int bkt[4], slot[4];
    if (valid) {
        s = ((const int4*)src)[i];
        d = ((const int4*)dst)[i];
        bkt[0] = d.x >> 8; slot[0] = atomicAdd(&lcnt[bkt[0]], 1);
        bkt[1] = d.y >> 8; slot[1] = atomicAdd(&lcnt[bkt[1]], 1);
        bkt[2] = d.z >> 8; slot[2] = atomicAdd(&lcnt[bkt[2]], 1);
        bkt[3] = d.w >> 8; slot[3] = atomicAdd(&lcnt[bkt[3]], 1);
    }
    __syncthreads();
    if (tid < NBUCK) {
        int c = lcnt[tid];
        lbase[tid] = c ? atomicAdd(&bcursor[tid], c) : 0;
    }
    __syncthreads();
    if (valid) {
        pairs[lbase[bkt[0]] + slot[0]] = (s.x) | ((d.x & 255) << 16);
        pairs[lbase[bkt[1]] + slot[1]] = (s.y) | ((d.y & 255) << 16);
        pairs[lbase[bkt[2]] + slot[2]] = (s.z) | ((d.z & 255) << 16);
        pairs[lbase[bkt[3]] + slot[3]] = (s.w) | ((d.w & 255) << 16);
    }
}

// ---------------------------------------------------------------------------
// Stage 2 fused with gather: one block per bucket (1024 thr = 16 waves).
// Build the bucket's CSR slice in LDS (LDS cursor atomics), then 16 waves
// gather 16 nodes each -> write agg rows in bf16.
// ---------------------------------------------------------------------------
__global__ void __launch_bounds__(1024)
bucket_gather(const ushort* __restrict__ xb, const int* __restrict__ pairs,
              const int* __restrict__ blockoff, const int* __restrict__ off,
              ushort* __restrict__ aggb) {
    __shared__ int loff[257];
    __shared__ int lcur[256];
    __shared__ int lsrc[BCAP];

    const int b   = blockIdx.x;
    const int tid = threadIdx.x;
    const int base_node  = b * 256;
    const int bucket_beg = blockoff[b];
    const int bucket_end = (b == NBUCK - 1) ? N_EDGES : blockoff[b + 1];

    if (tid <= 256) {
        int gn = base_node + tid;
        if (gn > N_NODES) gn = N_NODES;
        int v = off[gn] - bucket_beg;
        loff[tid] = v;
        if (tid < 256) lcur[tid] = v;
    }
    __syncthreads();

    for (int i = bucket_beg + tid; i < bucket_end; i += 1024) {
        int p = pairs[i];
        int local = p >> 16;                    // dst & 255 (bits 16..23)
        int pos = atomicAdd(&lcur[local], 1);
        if (pos < BCAP) lsrc[pos] = p & 0xFFFF; // src (< 2^16)
    }
    __syncthreads();

    const int lane = tid & 63;
    const int wv   = tid >> 6;
    const int h    = lane >> 5;
    const int c    = (lane & 31) << 2;          // bf16 col 0..124
    const ushort* xbb = xb + c;

#pragma unroll 1
    for (int j = 0; j < 16; ++j) {
        int ln = wv + j * 16;
        int gn = base_node + ln;
        if (gn >= N_NODES) break;
        int e    = loff[ln];
        int lend = loff[ln + 1];
        float4 acc = make_float4(0.f, 0.f, 0.f, 0.f);
        for (; e + 3 < lend; e += 4) {          // 2 rows per half, 2-deep
            int s0 = lsrc[e + h];               // LDS broadcast (free)
            int s1 = lsrc[e + 2 + h];
            ushort4 u0 = *(const ushort4*)(xbb + (size_t)s0 * D);
            ushort4 u1 = *(const ushort4*)(xbb + (size_t)s1 * D);
            acc.x += bf2f(u0.x) + bf2f(u1.x);
            acc.y += bf2f(u0.y) + bf2f(u1.y);
            acc.z += bf2f(u0.z) + bf2f(u1.z);
            acc.w += bf2f(u0.w) + bf2f(u1.w);
        }
        for (; e + 1 < lend; e += 2) {
            int s = lsrc[e + h];
            ushort4 u = *(const ushort4*)(xbb + (size_t)s * D);
            acc.x += bf2f(u.x); acc.y += bf2f(u.y);
            acc.z += bf2f(u.z); acc.w += bf2f(u.w);
        }
        if (e < lend && h == 0) {
            int s = lsrc[e];
            ushort4 u = *(const ushort4*)(xbb + (size_t)s * D);
            acc.x += bf2f(u.x); acc.y += bf2f(u.y);
            acc.z += bf2f(u.z); acc.w += bf2f(u.w);
        }
        acc.x += __shfl_xor(acc.x, 32, 64);
        acc.y += __shfl_xor(acc.y, 32, 64);
        acc.z += __shfl_xor(acc.z, 32, 64);
        acc.w += __shfl_xor(acc.w, 32, 64);
        if (h == 0) {
            ushort4 u = make_ushort4(f2bf(acc.x), f2bf(acc.y),
                                     f2bf(acc.z), f2bf(acc.w));
            *(ushort4*)(aggb + (size_t)gn * D + c) = u;  // 256B contiguous
        }
    }
}

// ---------------------------------------------------------------------------
// MFMA GEMM: out[n][o] = relu(sum_k aggb[n][k]*W[o][k]) + x[n][o].
// A-fragments loaded DIRECTLY from global bf16 agg (no LDS staging).
// Verified tile (R5-R8): A[m=lane&15][k=q*8+j], B = W row-major => agg @ W.T,
// C/D row = q*4+r, col = t*16+m16. LDS: Wl 32KB, epilogue overlay 33KB.
// ---------------------------------------------------------------------------
__global__ void __launch_bounds__(256)
gemm_relu_res(const ushort* __restrict__ aggb,
              const float* __restrict__ W,
              const float* __restrict__ x,
              float* __restrict__ out) {
    __shared__ __align__(16) char lds[33792];
    ushort* Wl = (ushort*)lds;                   // chunk-major [k/8][o][8]

    const int tid  = threadIdx.x;
    const int lane = tid & 63;
    const int wv   = tid >> 6;
    const int m16  = lane & 15;
    const int q    = lane >> 4;

#pragma unroll
    for (int i = 0; i < 8; ++i) {
        int g  = tid + i * 256;
        int o  = g & 127;
        int kc = g >> 7;
        const float4* wp = (const float4*)(W + (size_t)o * D + kc * 8);
        float4 w0 = wp[0], w1 = wp[1];
        bf16x8 hv;
        hv[0] = (short)f2bf(w0.x); hv[1] = (short)f2bf(w0.y);
        hv[2] = (short)f2bf(w0.z); hv[3] = (short)f2bf(w0.w);
        hv[4] = (short)f2bf(w1.x); hv[5] = (short)f2bf(w1.y);
        hv[6] = (short)f2bf(w1.z); hv[7] = (short)f2bf(w1.w);
        *(bf16x8*)&Wl[g * 8] = hv;
    }
    __syncthreads();

    const int nb = blockIdx.x * 64 + wv * 16;
    int arow = nb + m16;
    if (arow >= N_NODES) arow = N_NODES - 1;     // clamp: rows >= N never stored

    bf16x8 a[4];
#pragma unroll
    for (int kb = 0; kb < 4; ++kb)
        a[kb] = *(const bf16x8*)&aggb[(size_t)arow * D + kb * 32 + q * 8];

    f32x4 acc[8];
#pragma unroll
    for (int t = 0; t < 8; ++t) {
        acc[t] = (f32x4){0.f, 0.f, 0.f, 0.f};
#pragma unroll
        for (int kb = 0; kb < 4; ++kb) {
            bf16x8 bfr = *(const bf16x8*)&Wl[(((kb * 4 + q) * 128) + t * 16 + m16) * 8];
            acc[t] = __builtin_amdgcn_mfma_f32_16x16x32_bf16(a[kb], bfr, acc[t], 0, 0, 0);
        }
    }

    __syncthreads();                              // Wl dead after this
    float* Ew = (float*)(lds + wv * 8448);        // 16 rows x 132 floats
#pragma unroll
    for (int t = 0; t < 8; ++t)
#pragma unroll
        for (int r = 0; r < 4; ++r)
            Ew[(q * 4 + r) * 132 + t * 16 + m16] = acc[t][r];

    const int h  = lane >> 5;
    const int c4 = (lane & 31) << 2;
#pragma unroll
    for (int j = 0; j < 8; ++j) {
        int r = j * 2 + h;
        int node = nb + r;
        if (node < N_NODES) {
            float4 v  = *(const float4*)&Ew[r * 132 + c4];
            float4 xi = *(const float4*)(x + (size_t)node * D + c4);
            float4 o;
            o.x = fmaxf(v.x, 0.f) + xi.x;
            o.y = fmaxf(v.y, 0.f) + xi.y;
            o.z = fmaxf(v.z, 0.f) + xi.z;
            o.w = fmaxf(v.w, 0.f) + xi.w;
            *(float4*)(out + (size_t)node * D + c4) = o;
        }
    }
}

// ===================== fallback path (small ws) =====================
__global__ void __launch_bounds__(256)
build_sorted(const int* __restrict__ src, const int* __restrict__ dst,
             int* __restrict__ cursor, int* __restrict__ sorted_src) {
    int i = blockIdx.x * 256 + threadIdx.x;
    if (i >= N_EDGES / 4) return;
    int4 s = ((const int4*)src)[i];
    int4 d = ((const int4*)dst)[i];
    sorted_src[atomicAdd(&cursor[d.x], 1)] = s.x;
    sorted_src[atomicAdd(&cursor[d.y], 1)] = s.y;
    sorted_src[atomicAdd(&cursor[d.z], 1)] = s.z;
    sorted_src[atomicAdd(&cursor[d.w], 1)] = s.w;
}

__global__ void __launch_bounds__(256)
gather_sum_f32(const float* __restrict__ x,
               const int* __restrict__ sorted_src,
               const int* __restrict__ off,
               float* __restrict__ agg) {
    int node = (int)((blockIdx.x * 256 + threadIdx.x) >> 6);
    int lane = threadIdx.x & 63;
    if (node >= N_NODES) return;
    const int h  = lane >> 5;
    const int c4 = (lane & 31) << 2;
    const float* xbp = x + c4;
    int beg = off[node], end = off[node + 1];
    float4 acc = make_float4(0.f, 0.f, 0.f, 0.f);
    for (int base = beg; base < end; base += 64) {
        int n = end - base;
        if (n > 64) n = 64;
        int idx = (lane < n) ? sorted_src[base + lane] : 0;
        int npairs = n >> 1;
        int p = 0;
        for (; p < npairs; ++p) {
            int s = __shfl(idx, 2 * p + h, 64);
            float4 v = *(const float4*)(xbp + (size_t)s * D);
            acc.x += v.x; acc.y += v.y; acc.z += v.z; acc.w += v.w;
        }
        if (n & 1) {
            int s = __shfl(idx, n - 1, 64);
            if (h == 0) {
                float4 v = *(const float4*)(xbp + (size_t)s * D);
                acc.x += v.x; acc.y += v.y; acc.z += v.z; acc.w += v.w;
            }
        }
    }
    acc.x += __shfl_xor(acc.x, 32, 64);
    acc.y += __shfl_xor(acc.y, 32, 64);
    acc.z += __shfl_xor(acc.z, 32, 64);
    acc.w += __shfl_xor(acc.w, 32, 64);
    if (h == 0)
        *(float4*)(agg + (size_t)node * D + c4) = acc;
}

// fallback GEMM: in place on d_out, fp32 agg, LDS A staging (R7 version)
__global__ void __launch_bounds__(256)
gemm_relu_res_f32(float* data, const float* __restrict__ W,
                  const float* __restrict__ x) {
    __shared__ __align__(16) char lds[50176];
    ushort* Wl = (ushort*)lds;
    ushort* Al = (ushort*)(lds + 32768);

    const int tid  = threadIdx.x;
    const int lane = tid & 63;
    const int wv   = tid >> 6;
    const int m16  = lane & 15;
    const int q    = lane >> 4;

#pragma unroll
    for (int i = 0; i < 8; ++i) {
        int g  = tid + i * 256;
        int o  = g & 127;
        int kc = g >> 7;
        const float4* wp = (const float4*)(W + (size_t)o * D + kc * 8);
        float4 w0 = wp[0], w1 = wp[1];
        bf16x8 hv;
        hv[0] = (short)f2bf(w0.x); hv[1] = (short)f2bf(w0.y);
        hv[2] = (short)f2bf(w0.z); hv[3] = (short)f2bf(w0.w);
        hv[4] = (short)f2bf(w1.x); hv[5] = (short)f2bf(w1.y);
        hv[6] = (short)f2bf(w1.z); hv[7] = (short)f2bf(w1.w);
        *(bf16x8*)&Wl[g * 8] = hv;
    }
    __syncthreads();

    const int nb = blockIdx.x * 64 + wv * 16;
    ushort* Aw = &Al[wv * (16 * 136)];
#pragma unroll
    for (int m = 0; m < 16; ++m) {
        int node = nb + m;
        float2 v = make_float2(0.f, 0.f);
        if (node < N_NODES)
            v = *(const float2*)(data + (size_t)node * D + lane * 2);
        *(ushort2*)&Aw[m * 136 + lane * 2] = make_ushort2(f2bf(v.x), f2bf(v.y));
    }

    bf16x8 a[4];
#pragma unroll
    for (int kb = 0; kb < 4; ++kb)
        a[kb] = *(const bf16x8*)&Aw[m16 * 136 + kb * 32 + q * 8];

    f32x4 acc[8];
#pragma unroll
    for (int t = 0; t < 8; ++t) {
        acc[t] = (f32x4){0.f, 0.f, 0.f, 0.f};
#pragma unroll
        for (int kb = 0; kb < 4; ++kb) {
            bf16x8 bfr = *(const bf16x8*)&Wl[(((kb * 4 + q) * 128) + t * 16 + m16) * 8];
            acc[t] = __builtin_amdgcn_mfma_f32_16x16x32_bf16(a[kb], bfr, acc[t], 0, 0, 0);
        }
    }

    __syncthreads();
    float* Ew = (float*)(lds + wv * 8448);
#pragma unroll
    for (int t = 0; t < 8; ++t)
#pragma unroll
        for (int r = 0; r < 4; ++r)
            Ew[(q * 4 + r) * 132 + t * 16 + m16] = acc[t][r];

    const int h  = lane >> 5;
    const int c4 = (lane & 31) << 2;
#pragma unroll
    for (int j = 0; j < 8; ++j) {
        int r = j * 2 + h;
        int node = nb + r;
        if (node < N_NODES) {
            float4 v  = *(const float4*)&Ew[r * 132 + c4];
            float4 xi = *(const float4*)(x + (size_t)node * D + c4);
            float4 o;
            o.x = fmaxf(v.x, 0.f) + xi.x;
            o.y = fmaxf(v.y, 0.f) + xi.y;
            o.z = fmaxf(v.z, 0.f) + xi.z;
            o.w = fmaxf(v.w, 0.f) + xi.w;
            *(float4*)(data + (size_t)node * D + c4) = o;
        }
    }
}

extern "C" void kernel_launch(void* const* d_in, const int* in_sizes, int n_in,
                              void* d_out, int out_size, void* d_ws, size_t ws_size,
                              hipStream_t stream) {
    const float* x   = (const float*)d_in[0];
    const int*   src = (const int*)d_in[1];   // harness passes integers as int32
    const int*   dst = (const int*)d_in[2];
    const float* W   = (const float*)d_in[3];
    float* out = (float*)d_out;

    char* ws = (char*)d_ws;
    int* cnt      = (int*)ws;   ws += (size_t)N_NODES * 4;
    int* off      = (int*)ws;   ws += (size_t)(N_NODES + 1) * 4;
    int* cursor   = (int*)ws;   ws += (size_t)N_NODES * 4;
    int* blockoff = (int*)ws;   ws += (size_t)SCAN_NBLOCKS * 4;
    int* bcursor  = (int*)ws;   ws += (size_t)NBUCK * 4;
    int* pairs    = (int*)ws;   ws += (size_t)N_EDGES * 4;   // packed; doubles as sorted_src (fallback)
    ws = (char*)(((uintptr_t)ws + 15) & ~(uintptr_t)15);
    ushort* xb    = (ushort*)ws;  ws += (size_t)N_NODES * D * 2;
    ushort* aggb  = (ushort*)ws;  ws += (size_t)N_NODES * D * 2;
    const bool big_ws = (ws_size >= (size_t)(ws - (char*)d_ws));

    if (big_ws) {
        x_to_bf16<<<(N_NODES * D / 4 + 255) / 256, 256, 0, stream>>>(
            (const float4*)x, xb, cnt);
    } else {
        hipMemsetAsync(cnt, 0, (size_t)N_NODES * 4, stream);
    }

    histogram<<<(N_EDGES / 4 + 255) / 256, 256, 0, stream>>>(dst, cnt);
    scan_reduce<<<SCAN_NBLOCKS, 256, 0, stream>>>(cnt, blockoff /*blocksum*/);
    scan_partials<<<1, 256, 0, stream>>>(blockoff, blockoff, bcursor, off);
    scan_final<<<SCAN_NBLOCKS, 256, 0, stream>>>(cnt, blockoff, off, cursor);

    if (big_ws) {
        bucket_scatter<<<(N_EDGES / 4 + 1023) / 1024, 1024, 0, stream>>>(
            src, dst, bcursor, pairs);
        bucket_gather<<<NBUCK, 1024, 0, stream>>>(xb, pairs, blockoff, off, aggb);
        gemm_relu_res<<<(N_NODES + 63) / 64, 256, 0, stream>>>(aggb, W, x, out);
    } else {
        build_sorted<<<(N_EDGES / 4 + 255) / 256, 256, 0, stream>>>(
            src, dst, cursor, pairs /*as sorted_src*/);
        long long n_gather = (long long)N_NODES * 64;
        gather_sum_f32<<<(int)((n_gather + 255) / 256), 256, 0, stream>>>(
            x, pairs, off, out);
        gemm_relu_res_f32<<<(N_NODES + 63) / 64, 256, 0, stream>>>(out, W, x);
    }
}

// Round 10
// 149.885 us; speedup vs baseline: 2.0240x; 1.3320x over previous
//
#include <hip/hip_runtime.h>
#include <hip/hip_bf16.h>

#define N_NODES 50000
#define N_EDGES 800000
#define D 128

#define NBUCK 782        // bucket = dst>>6  (64 nodes); 49999>>6 = 781
#define BCAP  2048       // slots/bucket; count ~ 1023 +/- 32 (sd), +32sd margin

using bf16x8 = __attribute__((ext_vector_type(8))) short;   // 8 bf16 (4 VGPRs)
using u16x8  = __attribute__((ext_vector_type(8))) unsigned short;
using f32x4  = __attribute__((ext_vector_type(4))) float;   // MFMA C/D

static __device__ __forceinline__ ushort f2bf(float f) {
    __hip_bfloat16 h = __float2bfloat16(f);   // RNE
    return *reinterpret_cast<ushort*>(&h);
}
static __device__ __forceinline__ float bf2f(ushort u) {
    return __uint_as_float(((unsigned)u) << 16);
}

// ---------------------------------------------------------------------------
// ws layout (~36 MB): bcnt[NBUCK], pairs[NBUCK*BCAP] int,
//   sorted_u16[NBUCK*BCAP] ushort, off2[N_NODES] int2,
//   xb (bf16 x, 12.8 MB), aggb (bf16 agg, 12.8 MB).
// No global histogram/scan: buckets are fixed-capacity windows, per-node
// offsets are computed bucket-locally in LDS (64 counters + shfl scan).
// ---------------------------------------------------------------------------

// x -> bf16 copy; also zeroes bcnt (folds the memset away).
__global__ void __launch_bounds__(256)
x_to_bf16(const float4* __restrict__ x4, ushort* __restrict__ xb,
          int* __restrict__ bcnt) {
    int i = blockIdx.x * 256 + threadIdx.x;
    if (i < NBUCK) bcnt[i] = 0;
    if (i >= N_NODES * D / 4) return;
    float4 v = x4[i];
    ushort4 u = make_ushort4(f2bf(v.x), f2bf(v.y), f2bf(v.z), f2bf(v.w));
    *(ushort4*)(xb + (size_t)i * 4) = u;
}

// Cluster edges into 782 fixed-capacity dst-buckets (packed src|local<<16).
// LDS-aggregated reservations: one global atomic per (block, nonempty bucket).
__global__ void __launch_bounds__(1024)
bucket_scatter(const int* __restrict__ src, const int* __restrict__ dst,
               int* __restrict__ bcnt, int* __restrict__ pairs) {
    __shared__ int lcnt[NBUCK], lbase[NBUCK];
    const int tid = threadIdx.x;
    if (tid < NBUCK) lcnt[tid] = 0;
    __syncthreads();

    const int i = blockIdx.x * 1024 + tid;
    const bool valid = i < N_EDGES / 4;
    int4 s, d;
    int bkt[4], slot[4];
    if (valid) {
        s = ((const int4*)src)[i];
        d = ((const int4*)dst)[i];
        bkt[0] = d.x >> 6; slot[0] = atomicAdd(&lcnt[bkt[0]], 1);
        bkt[1] = d.y >> 6; slot[1] = atomicAdd(&lcnt[bkt[1]], 1);
        bkt[2] = d.z >> 6; slot[2] = atomicAdd(&lcnt[bkt[2]], 1);
        bkt[3] = d.w >> 6; slot[3] = atomicAdd(&lcnt[bkt[3]], 1);
    }
    __syncthreads();
    if (tid < NBUCK) {
        int c = lcnt[tid];
        lbase[tid] = c ? atomicAdd(&bcnt[tid], c) : 0;
    }
    __syncthreads();
    if (valid) {
#pragma unroll
        for (int e = 0; e < 4; ++e) {
            int sv = (e == 0) ? s.x : (e == 1) ? s.y : (e == 2) ? s.z : s.w;
            int dv = (e == 0) ? d.x : (e == 1) ? d.y : (e == 2) ? d.z : d.w;
            int pos = lbase[bkt[e]] + slot[e];
            if (pos < BCAP)                       // 32-sd guard, never trips
                pairs[bkt[e] * BCAP + pos] = sv | ((dv & 63) << 16);
        }
    }
}

// One block per bucket: LDS count(64) -> shfl scan -> place -> coalesced
// dump of ushort indices + off2[n] = (beg,end) into the bucket window.
__global__ void __launch_bounds__(256)
bucket_to_csr(const int* __restrict__ pairs, const int* __restrict__ bcnt,
              ushort* __restrict__ sorted_u16, int2* __restrict__ off2) {
    __shared__ int lcnt2[64], lcur[64];
    __shared__ ushort lsrc[BCAP];
    const int b    = blockIdx.x;
    const int tid  = threadIdx.x;
    const int base = b * BCAP;
    int n = bcnt[b];
    if (n > BCAP) n = BCAP;

    if (tid < 64) lcnt2[tid] = 0;
    __syncthreads();
    for (int i = tid; i < n; i += 256)
        atomicAdd(&lcnt2[pairs[base + i] >> 16], 1);
    __syncthreads();

    if (tid < 64) {                       // wave 0: 64-lane inclusive shfl scan
        int v = lcnt2[tid];
        int incl = v;
#pragma unroll
        for (int o = 1; o < 64; o <<= 1) {
            int t = __shfl_up(incl, o, 64);
            if (tid >= o) incl += t;
        }
        int excl = incl - v;
        lcur[tid] = excl;
        int gn = b * 64 + tid;
        if (gn < N_NODES)
            off2[gn] = make_int2(base + excl, base + incl);
    }
    __syncthreads();
    for (int i = tid; i < n; i += 256) {
        int p = pairs[base + i];
        int pos = atomicAdd(&lcur[p >> 16], 1);
        lsrc[pos] = (ushort)(p & 0xFFFF);
    }
    __syncthreads();
    for (int i = tid; i < n; i += 256)    // coalesced ushort dump
        sorted_u16[base + i] = lsrc[i];
}

// One wave per node. Quarter-wave rows: 16 lanes x ushort8 (16B) = one full
// 256B bf16 row; 4 edges/step; unroll 4 => 16 rows in flight per wave.
__global__ void __launch_bounds__(256)
gather_sum(const ushort* __restrict__ xb, const ushort* __restrict__ sorted_u16,
           const int2* __restrict__ off2, ushort* __restrict__ aggb) {
    int node = (int)((blockIdx.x * 256 + threadIdx.x) >> 6);
    int lane = threadIdx.x & 63;
    if (node >= N_NODES) return;
    const int q4 = lane >> 4;              // quarter 0..3 = edge slot in step
    const int c8 = (lane & 15) << 3;       // bf16 col 0,8,..,120
    const ushort* xbb = xb + c8;
    int2 oo = off2[node];
    int beg = oo.x, end = oo.y;

    float acc[8];
#pragma unroll
    for (int j = 0; j < 8; ++j) acc[j] = 0.f;

    for (int base = beg; base < end; base += 64) {
        int n = end - base;
        if (n > 64) n = 64;
        int idx = (lane < n) ? (int)sorted_u16[base + lane] : 0;  // coalesced
        int full = n >> 2;                 // steps of 4 edges
        int t = 0;
        for (; t + 4 <= full; t += 4) {    // 4 rows in flight per lane
            int s0 = __shfl(idx, 4 * t + q4, 64);
            int s1 = __shfl(idx, 4 * t + 4 + q4, 64);
            int s2 = __shfl(idx, 4 * t + 8 + q4, 64);
            int s3 = __shfl(idx, 4 * t + 12 + q4, 64);
            u16x8 u0 = *(const u16x8*)(xbb + (size_t)s0 * D);
            u16x8 u1 = *(const u16x8*)(xbb + (size_t)s1 * D);
            u16x8 u2 = *(const u16x8*)(xbb + (size_t)s2 * D);
            u16x8 u3 = *(const u16x8*)(xbb + (size_t)s3 * D);
#pragma unroll
            for (int j = 0; j < 8; ++j)
                acc[j] += (bf2f(u0[j]) + bf2f(u1[j])) + (bf2f(u2[j]) + bf2f(u3[j]));
        }
        for (; t < full; ++t) {
            int s = __shfl(idx, 4 * t + q4, 64);
            u16x8 u = *(const u16x8*)(xbb + (size_t)s * D);
#pragma unroll
            for (int j = 0; j < 8; ++j) acc[j] += bf2f(u[j]);
        }
        int rem = n & 3;
        if (rem) {
            int s = __shfl(idx, 4 * full + q4, 64);   // index < 64 always
            if (q4 < rem) {
                u16x8 u = *(const u16x8*)(xbb + (size_t)s * D);
#pragma unroll
                for (int j = 0; j < 8; ++j) acc[j] += bf2f(u[j]);
            }
        }
    }
    // merge quarters
#pragma unroll
    for (int j = 0; j < 8; ++j) {
        acc[j] += __shfl_xor(acc[j], 16, 64);
        acc[j] += __shfl_xor(acc[j], 32, 64);
    }
    if (q4 == 0) {
        u16x8 u;
#pragma unroll
        for (int j = 0; j < 8; ++j) u[j] = f2bf(acc[j]);
        *(u16x8*)(aggb + (size_t)node * D + c8) = u;   // 256B contiguous
    }
}

// ---------------------------------------------------------------------------
// MFMA GEMM (verified R5-R9): out[n][o] = relu(sum_k aggb[n][k]*W[o][k]) + x[n][o]
// A-fragments direct from global bf16 agg; B = W row-major => agg @ W.T.
// ---------------------------------------------------------------------------
__global__ void __launch_bounds__(256)
gemm_relu_res(const ushort* __restrict__ aggb,
              const float* __restrict__ W,
              const float* __restrict__ x,
              float* __restrict__ out) {
    __shared__ __align__(16) char lds[33792];
    ushort* Wl = (ushort*)lds;                   // chunk-major [k/8][o][8]

    const int tid  = threadIdx.x;
    const int lane = tid & 63;
    const int wv   = tid >> 6;
    const int m16  = lane & 15;
    const int q    = lane >> 4;

#pragma unroll
    for (int i = 0; i < 8; ++i) {
        int g  = tid + i * 256;
        int o  = g & 127;
        int kc = g >> 7;
        const float4* wp = (const float4*)(W + (size_t)o * D + kc * 8);
        float4 w0 = wp[0], w1 = wp[1];
        bf16x8 hv;
        hv[0] = (short)f2bf(w0.x); hv[1] = (short)f2bf(w0.y);
        hv[2] = (short)f2bf(w0.z); hv[3] = (short)f2bf(w0.w);
        hv[4] = (short)f2bf(w1.x); hv[5] = (short)f2bf(w1.y);
        hv[6] = (short)f2bf(w1.z); hv[7] = (short)f2bf(w1.w);
        *(bf16x8*)&Wl[g * 8] = hv;
    }
    __syncthreads();

    const int nb = blockIdx.x * 64 + wv * 16;
    int arow = nb + m16;
    if (arow >= N_NODES) arow = N_NODES - 1;     // clamp: rows >= N never stored

    bf16x8 a[4];
#pragma unroll
    for (int kb = 0; kb < 4; ++kb)
        a[kb] = *(const bf16x8*)&aggb[(size_t)arow * D + kb * 32 + q * 8];

    f32x4 acc[8];
#pragma unroll
    for (int t = 0; t < 8; ++t) {
        acc[t] = (f32x4){0.f, 0.f, 0.f, 0.f};
#pragma unroll
        for (int kb = 0; kb < 4; ++kb) {
            bf16x8 bfr = *(const bf16x8*)&Wl[(((kb * 4 + q) * 128) + t * 16 + m16) * 8];
            acc[t] = __builtin_amdgcn_mfma_f32_16x16x32_bf16(a[kb], bfr, acc[t], 0, 0, 0);
        }
    }

    __syncthreads();                              // Wl dead after this
    float* Ew = (float*)(lds + wv * 8448);        // 16 rows x 132 floats
#pragma unroll
    for (int t = 0; t < 8; ++t)
#pragma unroll
        for (int r = 0; r < 4; ++r)
            Ew[(q * 4 + r) * 132 + t * 16 + m16] = acc[t][r];

    const int h  = lane >> 5;
    const int c4 = (lane & 31) << 2;
#pragma unroll
    for (int j = 0; j < 8; ++j) {
        int r = j * 2 + h;
        int node = nb + r;
        if (node < N_NODES) {
            float4 v  = *(const float4*)&Ew[r * 132 + c4];
            float4 xi = *(const float4*)(x + (size_t)node * D + c4);
            float4 o;
            o.x = fmaxf(v.x, 0.f) + xi.x;
            o.y = fmaxf(v.y, 0.f) + xi.y;
            o.z = fmaxf(v.z, 0.f) + xi.z;
            o.w = fmaxf(v.w, 0.f) + xi.w;
            *(float4*)(out + (size_t)node * D + c4) = o;
        }
    }
}

// ===================== minimal fallback (tiny ws; never expected) ==========
__global__ void zero_out(float4* __restrict__ p, int n4) {
    int i = blockIdx.x * 256 + threadIdx.x;
    if (i < n4) p[i] = make_float4(0.f, 0.f, 0.f, 0.f);
}
__global__ void scatter_edges(const float* __restrict__ x,
                              const int* __restrict__ src,
                              const int* __restrict__ dst,
                              float* __restrict__ agg) {
    long long tid = (long long)blockIdx.x * 256 + threadIdx.x;
    if (tid >= (long long)N_EDGES * 32) return;
    int edge = (int)(tid >> 5);
    int c    = ((int)tid & 31) << 2;
    const float4 v = *(const float4*)(x + (size_t)src[edge] * D + c);
    float* p = agg + (size_t)dst[edge] * D + c;
    unsafeAtomicAdd(p + 0, v.x);
    unsafeAtomicAdd(p + 1, v.y);
    unsafeAtomicAdd(p + 2, v.z);
    unsafeAtomicAdd(p + 3, v.w);
}
__global__ void __launch_bounds__(256)
gemm_relu_res_f32(float* data, const float* __restrict__ W,
                  const float* __restrict__ x) {
    __shared__ __align__(16) char lds[50176];
    ushort* Wl = (ushort*)lds;
    ushort* Al = (ushort*)(lds + 32768);
    const int tid  = threadIdx.x;
    const int lane = tid & 63;
    const int wv   = tid >> 6;
    const int m16  = lane & 15;
    const int q    = lane >> 4;
#pragma unroll
    for (int i = 0; i < 8; ++i) {
        int g  = tid + i * 256;
        int o  = g & 127;
        int kc = g >> 7;
        const float4* wp = (const float4*)(W + (size_t)o * D + kc * 8);
        float4 w0 = wp[0], w1 = wp[1];
        bf16x8 hv;
        hv[0] = (short)f2bf(w0.x); hv[1] = (short)f2bf(w0.y);
        hv[2] = (short)f2bf(w0.z); hv[3] = (short)f2bf(w0.w);
        hv[4] = (short)f2bf(w1.x); hv[5] = (short)f2bf(w1.y);
        hv[6] = (short)f2bf(w1.z); hv[7] = (short)f2bf(w1.w);
        *(bf16x8*)&Wl[g * 8] = hv;
    }
    __syncthreads();
    const int nb = blockIdx.x * 64 + wv * 16;
    ushort* Aw = &Al[wv * (16 * 136)];
#pragma unroll
    for (int m = 0; m < 16; ++m) {
        int node = nb + m;
        float2 v = make_float2(0.f, 0.f);
        if (node < N_NODES)
            v = *(const float2*)(data + (size_t)node * D + lane * 2);
        *(ushort2*)&Aw[m * 136 + lane * 2] = make_ushort2(f2bf(v.x), f2bf(v.y));
    }
    bf16x8 a[4];
#pragma unroll
    for (int kb = 0; kb < 4; ++kb)
        a[kb] = *(const bf16x8*)&Aw[m16 * 136 + kb * 32 + q * 8];
    f32x4 acc[8];
#pragma unroll
    for (int t = 0; t < 8; ++t) {
        acc[t] = (f32x4){0.f, 0.f, 0.f, 0.f};
#pragma unroll
        for (int kb = 0; kb < 4; ++kb) {
            bf16x8 bfr = *(const bf16x8*)&Wl[(((kb * 4 + q) * 128) + t * 16 + m16) * 8];
            acc[t] = __builtin_amdgcn_mfma_f32_16x16x32_bf16(a[kb], bfr, acc[t], 0, 0, 0);
        }
    }
    __syncthreads();
    float* Ew = (float*)(lds + wv * 8448);
#pragma unroll
    for (int t = 0; t < 8; ++t)
#pragma unroll
        for (int r = 0; r < 4; ++r)
            Ew[(q * 4 + r) * 132 + t * 16 + m16] = acc[t][r];
    const int h  = lane >> 5;
    const int c4 = (lane & 31) << 2;
#pragma unroll
    for (int j = 0; j < 8; ++j) {
        int r = j * 2 + h;
        int node = nb + r;
        if (node < N_NODES) {
            float4 v  = *(const float4*)&Ew[r * 132 + c4];
            float4 xi = *(const float4*)(x + (size_t)node * D + c4);
            float4 o;
            o.x = fmaxf(v.x, 0.f) + xi.x;
            o.y = fmaxf(v.y, 0.f) + xi.y;
            o.z = fmaxf(v.z, 0.f) + xi.z;
            o.w = fmaxf(v.w, 0.f) + xi.w;
            *(float4*)(data + (size_t)node * D + c4) = o;
        }
    }
}

extern "C" void kernel_launch(void* const* d_in, const int* in_sizes, int n_in,
                              void* d_out, int out_size, void* d_ws, size_t ws_size,
                              hipStream_t stream) {
    const float* x   = (const float*)d_in[0];
    const int*   src = (const int*)d_in[1];   // harness passes integers as int32
    const int*   dst = (const int*)d_in[2];
    const float* W   = (const float*)d_in[3];
    float* out = (float*)d_out;

    char* ws = (char*)d_ws;
    int*    bcnt  = (int*)ws;        ws += (size_t)NBUCK * 4;
    ws = (char*)(((uintptr_t)ws + 15) & ~(uintptr_t)15);
    int*    pairs = (int*)ws;        ws += (size_t)NBUCK * BCAP * 4;
    ushort* su16  = (ushort*)ws;     ws += (size_t)NBUCK * BCAP * 2;
    int2*   off2  = (int2*)ws;       ws += (size_t)N_NODES * 8;
    ws = (char*)(((uintptr_t)ws + 15) & ~(uintptr_t)15);
    ushort* xb    = (ushort*)ws;     ws += (size_t)N_NODES * D * 2;
    ushort* aggb  = (ushort*)ws;     ws += (size_t)N_NODES * D * 2;
    const bool big_ws = (ws_size >= (size_t)(ws - (char*)d_ws));

    if (big_ws) {
        x_to_bf16<<<(N_NODES * D / 4 + 255) / 256, 256, 0, stream>>>(
            (const float4*)x, xb, bcnt);
        bucket_scatter<<<(N_EDGES / 4 + 1023) / 1024, 1024, 0, stream>>>(
            src, dst, bcnt, pairs);
        bucket_to_csr<<<NBUCK, 256, 0, stream>>>(pairs, bcnt, su16, off2);
        gather_sum<<<(N_NODES * 64 + 255) / 256, 256, 0, stream>>>(
            xb, su16, off2, aggb);
        gemm_relu_res<<<(N_NODES + 63) / 64, 256, 0, stream>>>(aggb, W, x, out);
    } else {
        // slow-but-correct fallback (no scratch needed beyond d_out)
        int n4 = N_NODES * D / 4;
        zero_out<<<(n4 + 255) / 256, 256, 0, stream>>>((float4*)out, n4);
        long long n_scatter = (long long)N_EDGES * 32;
        scatter_edges<<<(int)((n_scatter + 255) / 256), 256, 0, stream>>>(
            x, src, dst, out);
        gemm_relu_res_f32<<<(N_NODES + 63) / 64, 256, 0, stream>>>(out, W, x);
    }
}

// Round 12
// 148.582 us; speedup vs baseline: 2.0417x; 1.0088x over previous
//
#include <hip/hip_runtime.h>
#include <hip/hip_bf16.h>

#define N_NODES 50000
#define N_EDGES 800000
#define D 128

#define NBUCK 782        // bucket = dst>>6  (64 nodes); 49999>>6 = 781
#define BCAP  2048       // slots/bucket; count ~1023 +/- ~32 (sd); huge margin

#define SCAT_BLOCKS ((N_EDGES / 4 + 1023) / 1024)   // 196 — covers ALL edges

using bf16x8 = __attribute__((ext_vector_type(8))) short;   // 8 bf16 (4 VGPRs)
using u16x8  = __attribute__((ext_vector_type(8))) unsigned short;
using f32x4  = __attribute__((ext_vector_type(4))) float;   // MFMA C/D

static __device__ __forceinline__ ushort f2bf(float f) {
    __hip_bfloat16 h = __float2bfloat16(f);   // RNE
    return *reinterpret_cast<ushort*>(&h);
}
static __device__ __forceinline__ float bf2f(ushort u) {
    return __uint_as_float(((unsigned)u) << 16);
}

// ---------------------------------------------------------------------------
// ws layout (~36 MB): bcnt[NBUCK], pairs[NBUCK*BCAP] int,
//   sorted_u16[NBUCK*BCAP] ushort, off2[N_NODES] int2,
//   xb (bf16 x, 12.8 MB), aggb (bf16 agg, 12.8 MB).
// Fixed-capacity buckets: no global histogram/scan. Per-node offsets are
// computed bucket-locally in LDS (64 counters + shfl scan).
// ---------------------------------------------------------------------------

// Fused: x -> bf16 conversion (grid-stride) + bucket scatter of edges.
// R11 bug fixed: grid must cover N_EDGES/4 threads (196 blocks, not 195);
// conversion stride now derived from gridDim.x so they can't diverge.
__global__ void __launch_bounds__(1024)
convert_scatter(const float4* __restrict__ x4, ushort* __restrict__ xb,
                const int* __restrict__ src, const int* __restrict__ dst,
                int* __restrict__ bcnt, int* __restrict__ pairs) {
    __shared__ int lcnt[NBUCK], lbase[NBUCK];
    const int tid = threadIdx.x;
    if (tid < NBUCK) lcnt[tid] = 0;

    // issue edge loads early (latency overlapped with conversion below)
    const int i = blockIdx.x * 1024 + tid;
    const bool valid = i < N_EDGES / 4;
    int4 s, d;
    if (valid) {
        s = ((const int4*)src)[i];
        d = ((const int4*)dst)[i];
    }

    // streaming conversion: 1.6M float4, grid-stride over the actual grid
    const int total4 = N_NODES * D / 4;
    const int stride = gridDim.x * 1024;
    for (int j = blockIdx.x * 1024 + tid; j < total4; j += stride) {
        float4 v = x4[j];
        ushort4 u = make_ushort4(f2bf(v.x), f2bf(v.y), f2bf(v.z), f2bf(v.w));
        *(ushort4*)(xb + (size_t)j * 4) = u;
    }
    __syncthreads();          // lcnt zeros visible

    int bkt[4], slot[4];
    if (valid) {
        bkt[0] = d.x >> 6; slot[0] = atomicAdd(&lcnt[bkt[0]], 1);
        bkt[1] = d.y >> 6; slot[1] = atomicAdd(&lcnt[bkt[1]], 1);
        bkt[2] = d.z >> 6; slot[2] = atomicAdd(&lcnt[bkt[2]], 1);
        bkt[3] = d.w >> 6; slot[3] = atomicAdd(&lcnt[bkt[3]], 1);
    }
    __syncthreads();
    if (tid < NBUCK) {
        int c = lcnt[tid];
        lbase[tid] = c ? atomicAdd(&bcnt[tid], c) : 0;
    }
    __syncthreads();
    if (valid) {
#pragma unroll
        for (int e = 0; e < 4; ++e) {
            int sv = (e == 0) ? s.x : (e == 1) ? s.y : (e == 2) ? s.z : s.w;
            int dv = (e == 0) ? d.x : (e == 1) ? d.y : (e == 2) ? d.z : d.w;
            int pos = lbase[bkt[e]] + slot[e];
            if (pos < BCAP)                       // ~32-sd guard, never trips
                pairs[bkt[e] * BCAP + pos] = sv | ((dv & 63) << 16);
        }
    }
}

// One block per bucket: LDS count(64) -> shfl scan -> place -> coalesced
// dump of ushort indices + off2[n] = (beg,end) into the bucket window.
__global__ void __launch_bounds__(256)
bucket_to_csr(const int* __restrict__ pairs, const int* __restrict__ bcnt,
              ushort* __restrict__ sorted_u16, int2* __restrict__ off2) {
    __shared__ int lcnt2[64], lcur[64];
    __shared__ ushort lsrc[BCAP];
    const int b    = blockIdx.x;
    const int tid  = threadIdx.x;
    const int base = b * BCAP;
    int n = bcnt[b];
    if (n > BCAP) n = BCAP;

    if (tid < 64) lcnt2[tid] = 0;
    __syncthreads();
    for (int i = tid; i < n; i += 256)
        atomicAdd(&lcnt2[pairs[base + i] >> 16], 1);
    __syncthreads();

    if (tid < 64) {                       // wave 0: 64-lane inclusive shfl scan
        int v = lcnt2[tid];
        int incl = v;
#pragma unroll
        for (int o = 1; o < 64; o <<= 1) {
            int t = __shfl_up(incl, o, 64);
            if (tid >= o) incl += t;
        }
        int excl = incl - v;
        lcur[tid] = excl;
        int gn = b * 64 + tid;
        if (gn < N_NODES)
            off2[gn] = make_int2(base + excl, base + incl);
    }
    __syncthreads();
    for (int i = tid; i < n; i += 256) {
        int p = pairs[base + i];
        int pos = atomicAdd(&lcur[p >> 16], 1);
        lsrc[pos] = (ushort)(p & 0xFFFF);
    }
    __syncthreads();
    for (int i = tid; i < n; i += 256)    // coalesced ushort dump
        sorted_u16[base + i] = lsrc[i];
}

// One wave per node. Quarter-wave rows: 16 lanes x ushort8 (16B) = one full
// 256B bf16 row; 4 edges/step; unroll 4 => 16 rows in flight per wave.
__global__ void __launch_bounds__(256)
gather_sum(const ushort* __restrict__ xb, const ushort* __restrict__ sorted_u16,
           const int2* __restrict__ off2, ushort* __restrict__ aggb) {
    int node = (int)((blockIdx.x * 256 + threadIdx.x) >> 6);
    int lane = threadIdx.x & 63;
    if (node >= N_NODES) return;
    const int q4 = lane >> 4;              // quarter 0..3 = edge slot in step
    const int c8 = (lane & 15) << 3;       // bf16 col 0,8,..,120
    const ushort* xbb = xb + c8;
    int2 oo = off2[node];
    int beg = oo.x, end = oo.y;

    float acc[8];
#pragma unroll
    for (int j = 0; j < 8; ++j) acc[j] = 0.f;

    for (int base = beg; base < end; base += 64) {
        int n = end - base;
        if (n > 64) n = 64;
        int idx = (lane < n) ? (int)sorted_u16[base + lane] : 0;  // coalesced
        int full = n >> 2;                 // steps of 4 edges
        int t = 0;
        for (; t + 4 <= full; t += 4) {    // 4 rows in flight per lane
            int s0 = __shfl(idx, 4 * t + q4, 64);
            int s1 = __shfl(idx, 4 * t + 4 + q4, 64);
            int s2 = __shfl(idx, 4 * t + 8 + q4, 64);
            int s3 = __shfl(idx, 4 * t + 12 + q4, 64);
            u16x8 u0 = *(const u16x8*)(xbb + (size_t)s0 * D);
            u16x8 u1 = *(const u16x8*)(xbb + (size_t)s1 * D);
            u16x8 u2 = *(const u16x8*)(xbb + (size_t)s2 * D);
            u16x8 u3 = *(const u16x8*)(xbb + (size_t)s3 * D);
#pragma unroll
            for (int j = 0; j < 8; ++j)
                acc[j] += (bf2f(u0[j]) + bf2f(u1[j])) + (bf2f(u2[j]) + bf2f(u3[j]));
        }
        for (; t < full; ++t) {
            int s = __shfl(idx, 4 * t + q4, 64);
            u16x8 u = *(const u16x8*)(xbb + (size_t)s * D);
#pragma unroll
            for (int j = 0; j < 8; ++j) acc[j] += bf2f(u[j]);
        }
        int rem = n & 3;
        if (rem) {
            int s = __shfl(idx, 4 * full + q4, 64);   // index < 64 always
            if (q4 < rem) {
                u16x8 u = *(const u16x8*)(xbb + (size_t)s * D);
#pragma unroll
                for (int j = 0; j < 8; ++j) acc[j] += bf2f(u[j]);
            }
        }
    }
#pragma unroll
    for (int j = 0; j < 8; ++j) {
        acc[j] += __shfl_xor(acc[j], 16, 64);
        acc[j] += __shfl_xor(acc[j], 32, 64);
    }
    if (q4 == 0) {
        u16x8 u;
#pragma unroll
        for (int j = 0; j < 8; ++j) u[j] = f2bf(acc[j]);
        *(u16x8*)(aggb + (size_t)node * D + c8) = u;   // 256B contiguous
    }
}

// ---------------------------------------------------------------------------
// MFMA GEMM (verified R5-R10): out[n][o] = relu(sum_k aggb[n][k]*W[o][k]) + x[n][o]
// A-fragments direct from global bf16 agg; B = W row-major => agg @ W.T.
// Residual read from xb (bf16): halves epilogue read traffic.
// ---------------------------------------------------------------------------
__global__ void __launch_bounds__(256)
gemm_relu_res(const ushort* __restrict__ aggb,
              const float* __restrict__ W,
              const ushort* __restrict__ xb,
              float* __restrict__ out) {
    __shared__ __align__(16) char lds[33792];
    ushort* Wl = (ushort*)lds;                   // chunk-major [k/8][o][8]

    const int tid  = threadIdx.x;
    const int lane = tid & 63;
    const int wv   = tid >> 6;
    const int m16  = lane & 15;
    const int q    = lane >> 4;

#pragma unroll
    for (int i = 0; i < 8; ++i) {
        int g  = tid + i * 256;
        int o  = g & 127;
        int kc = g >> 7;
        const float4* wp = (const float4*)(W + (size_t)o * D + kc * 8);
        float4 w0 = wp[0], w1 = wp[1];
        bf16x8 hv;
        hv[0] = (short)f2bf(w0.x); hv[1] = (short)f2bf(w0.y);
        hv[2] = (short)f2bf(w0.z); hv[3] = (short)f2bf(w0.w);
        hv[4] = (short)f2bf(w1.x); hv[5] = (short)f2bf(w1.y);
        hv[6] = (short)f2bf(w1.z); hv[7] = (short)f2bf(w1.w);
        *(bf16x8*)&Wl[g * 8] = hv;
    }
    __syncthreads();

    const int nb = blockIdx.x * 64 + wv * 16;
    int arow = nb + m16;
    if (arow >= N_NODES) arow = N_NODES - 1;     // clamp: rows >= N never stored

    bf16x8 a[4];
#pragma unroll
    for (int kb = 0; kb < 4; ++kb)
        a[kb] = *(const bf16x8*)&aggb[(size_t)arow * D + kb * 32 + q * 8];

    f32x4 acc[8];
#pragma unroll
    for (int t = 0; t < 8; ++t) {
        acc[t] = (f32x4){0.f, 0.f, 0.f, 0.f};
#pragma unroll
        for (int kb = 0; kb < 4; ++kb) {
            bf16x8 bfr = *(const bf16x8*)&Wl[(((kb * 4 + q) * 128) + t * 16 + m16) * 8];
            acc[t] = __builtin_amdgcn_mfma_f32_16x16x32_bf16(a[kb], bfr, acc[t], 0, 0, 0);
        }
    }

    __syncthreads();                              // Wl dead after this
    float* Ew = (float*)(lds + wv * 8448);        // 16 rows x 132 floats
#pragma unroll
    for (int t = 0; t < 8; ++t)
#pragma unroll
        for (int r = 0; r < 4; ++r)
            Ew[(q * 4 + r) * 132 + t * 16 + m16] = acc[t][r];

    const int h  = lane >> 5;
    const int c4 = (lane & 31) << 2;
#pragma unroll
    for (int j = 0; j < 8; ++j) {
        int r = j * 2 + h;
        int node = nb + r;
        if (node < N_NODES) {
            float4 v  = *(const float4*)&Ew[r * 132 + c4];
            ushort4 xu = *(const ushort4*)(xb + (size_t)node * D + c4);
            float4 o;
            o.x = fmaxf(v.x, 0.f) + bf2f(xu.x);
            o.y = fmaxf(v.y, 0.f) + bf2f(xu.y);
            o.z = fmaxf(v.z, 0.f) + bf2f(xu.z);
            o.w = fmaxf(v.w, 0.f) + bf2f(xu.w);
            *(float4*)(out + (size_t)node * D + c4) = o;
        }
    }
}

// ===================== minimal fallback (tiny ws; never expected) ==========
__global__ void zero_out(float4* __restrict__ p, int n4) {
    int i = blockIdx.x * 256 + threadIdx.x;
    if (i < n4) p[i] = make_float4(0.f, 0.f, 0.f, 0.f);
}
__global__ void scatter_edges(const float* __restrict__ x,
                              const int* __restrict__ src,
                              const int* __restrict__ dst,
                              float* __restrict__ agg) {
    long long tid = (long long)blockIdx.x * 256 + threadIdx.x;
    if (tid >= (long long)N_EDGES * 32) return;
    int edge = (int)(tid >> 5);
    int c    = ((int)tid & 31) << 2;
    const float4 v = *(const float4*)(x + (size_t)src[edge] * D + c);
    float* p = agg + (size_t)dst[edge] * D + c;
    unsafeAtomicAdd(p + 0, v.x);
    unsafeAtomicAdd(p + 1, v.y);
    unsafeAtomicAdd(p + 2, v.z);
    unsafeAtomicAdd(p + 3, v.w);
}
__global__ void __launch_bounds__(256)
gemm_relu_res_f32(float* data, const float* __restrict__ W,
                  const float* __restrict__ x) {
    __shared__ __align__(16) char lds[50176];
    ushort* Wl = (ushort*)lds;
    ushort* Al = (ushort*)(lds + 32768);
    const int tid  = threadIdx.x;
    const int lane = tid & 63;
    const int wv   = tid >> 6;
    const int m16  = lane & 15;
    const int q    = lane >> 4;
#pragma unroll
    for (int i = 0; i < 8; ++i) {
        int g  = tid + i * 256;
        int o  = g & 127;
        int kc = g >> 7;
        const float4* wp = (const float4*)(W + (size_t)o * D + kc * 8);
        float4 w0 = wp[0], w1 = wp[1];
        bf16x8 hv;
        hv[0] = (short)f2bf(w0.x); hv[1] = (short)f2bf(w0.y);
        hv[2] = (short)f2bf(w0.z); hv[3] = (short)f2bf(w0.w);
        hv[4] = (short)f2bf(w1.x); hv[5] = (short)f2bf(w1.y);
        hv[6] = (short)f2bf(w1.z); hv[7] = (short)f2bf(w1.w);
        *(bf16x8*)&Wl[g * 8] = hv;
    }
    __syncthreads();
    const int nb = blockIdx.x * 64 + wv * 16;
    ushort* Aw = &Al[wv * (16 * 136)];
#pragma unroll
    for (int m = 0; m < 16; ++m) {
        int node = nb + m;
        float2 v = make_float2(0.f, 0.f);
        if (node < N_NODES)
            v = *(const float2*)(data + (size_t)node * D + lane * 2);
        *(ushort2*)&Aw[m * 136 + lane * 2] = make_ushort2(f2bf(v.x), f2bf(v.y));
    }
    bf16x8 a[4];
#pragma unroll
    for (int kb = 0; kb < 4; ++kb)
        a[kb] = *(const bf16x8*)&Aw[m16 * 136 + kb * 32 + q * 8];
    f32x4 acc[8];
#pragma unroll
    for (int t = 0; t < 8; ++t) {
        acc[t] = (f32x4){0.f, 0.f, 0.f, 0.f};
#pragma unroll
        for (int kb = 0; kb < 4; ++kb) {
            bf16x8 bfr = *(const bf16x8*)&Wl[(((kb * 4 + q) * 128) + t * 16 + m16) * 8];
            acc[t] = __builtin_amdgcn_mfma_f32_16x16x32_bf16(a[kb], bfr, acc[t], 0, 0, 0);
        }
    }
    __syncthreads();
    float* Ew = (float*)(lds + wv * 8448);
#pragma unroll
    for (int t = 0; t < 8; ++t)
#pragma unroll
        for (int r = 0; r < 4; ++r)
            Ew[(q * 4 + r) * 132 + t * 16 + m16] = acc[t][r];
    const int h  = lane >> 5;
    const int c4 = (lane & 31) << 2;
#pragma unroll
    for (int j = 0; j < 8; ++j) {
        int r = j * 2 + h;
        int node = nb + r;
        if (node < N_NODES) {
            float4 v  = *(const float4*)&Ew[r * 132 + c4];
            float4 xi = *(const float4*)(x + (size_t)node * D + c4);
            float4 o;
            o.x = fmaxf(v.x, 0.f) + xi.x;
            o.y = fmaxf(v.y, 0.f) + xi.y;
            o.z = fmaxf(v.z, 0.f) + xi.z;
            o.w = fmaxf(v.w, 0.f) + xi.w;
            *(float4*)(data + (size_t)node * D + c4) = o;
        }
    }
}

extern "C" void kernel_launch(void* const* d_in, const int* in_sizes, int n_in,
                              void* d_out, int out_size, void* d_ws, size_t ws_size,
                              hipStream_t stream) {
    const float* x   = (const float*)d_in[0];
    const int*   src = (const int*)d_in[1];   // harness passes integers as int32
    const int*   dst = (const int*)d_in[2];
    const float* W   = (const float*)d_in[3];
    float* out = (float*)d_out;

    char* ws = (char*)d_ws;
    int*    bcnt  = (int*)ws;        ws += (size_t)NBUCK * 4;
    ws = (char*)(((uintptr_t)ws + 15) & ~(uintptr_t)15);
    int*    pairs = (int*)ws;        ws += (size_t)NBUCK * BCAP * 4;
    ushort* su16  = (ushort*)ws;     ws += (size_t)NBUCK * BCAP * 2;
    int2*   off2  = (int2*)ws;       ws += (size_t)N_NODES * 8;
    ws = (char*)(((uintptr_t)ws + 15) & ~(uintptr_t)15);
    ushort* xb    = (ushort*)ws;     ws += (size_t)N_NODES * D * 2;
    ushort* aggb  = (ushort*)ws;     ws += (size_t)N_NODES * D * 2;
    const bool big_ws = (ws_size >= (size_t)(ws - (char*)d_ws));

    if (big_ws) {
        hipMemsetAsync(bcnt, 0, (size_t)NBUCK * 4, stream);   // 3 KB fill
        convert_scatter<<<SCAT_BLOCKS, 1024, 0, stream>>>(     // 196 blocks!
            (const float4*)x, xb, src, dst, bcnt, pairs);
        bucket_to_csr<<<NBUCK, 256, 0, stream>>>(pairs, bcnt, su16, off2);
        gather_sum<<<(N_NODES * 64 + 255) / 256, 256, 0, stream>>>(
            xb, su16, off2, aggb);
        gemm_relu_res<<<(N_NODES + 63) / 64, 256, 0, stream>>>(aggb, W, xb, out);
    } else {
        // slow-but-correct fallback (no scratch needed beyond d_out)
        int n4 = N_NODES * D / 4;
        zero_out<<<(n4 + 255) / 256, 256, 0, stream>>>((float4*)out, n4);
        long long n_scatter = (long long)N_EDGES * 32;
        scatter_edges<<<(int)((n_scatter + 255) / 256), 256, 0, stream>>>(
            x, src, dst, out);
        gemm_relu_res_f32<<<(N_NODES + 63) / 64, 256, 0, stream>>>(out, W, x);
    }
}